// Round 1
// baseline (1470.789 us; speedup 1.0000x reference)
//
#include <hip/hip_runtime.h>
#include <math.h>

#define NN 50000
#define EE 800000
#define IN_F 200
#define DD 127
#define GG 512
#define EPSH 1e-5f

__device__ __forceinline__ float wsum(float v) {
#pragma unroll
  for (int off = 32; off > 0; off >>= 1) v += __shfl_xor(v, off);
  return v;
}

// ---------------- prep: transpose weights, pad w_in ----------------
__global__ void k_prep_w(const float* __restrict__ att_w, const float* __restrict__ mlp_w,
                         const float* __restrict__ w_in, float* __restrict__ Wt,
                         float* __restrict__ winp) {
  int b = blockIdx.x, tid = threadIdx.x;
  if (b < 6) {
    const float* src = (b < 2) ? att_w + b * DD * DD : mlp_w + (b - 2) * DD * DD;
    float* dst = Wt + b * 16384;
    for (int f = tid; f < 16384; f += 256) {
      int k = f >> 7, j = f & 127;
      dst[f] = (k < DD && j < DD) ? src[j * DD + k] : 0.f;
    }
  } else {
    for (int f = tid; f < IN_F * 128; f += 256) {
      int k = f >> 7, j = f & 127;
      winp[f] = (j < DD) ? w_in[k * DD + j] : 0.f;
    }
  }
}

// ---------------- CSR build ----------------
__global__ void k_count(const int* __restrict__ idx, int n, int* __restrict__ cnt) {
  int i = blockIdx.x * blockDim.x + threadIdx.x;
  if (i < n) atomicAdd(&cnt[idx[i]], 1);
}

__global__ __launch_bounds__(1024) void k_scan_excl(const int* __restrict__ in, int n,
                                                    int* __restrict__ out, int* __restrict__ cur) {
  __shared__ int wbase[16];
  __shared__ int chunk_tot;
  int tid = threadIdx.x;
  int lane = tid & 63;
  int w = tid >> 6;
  int carry = 0;
  for (int base = 0; base < n; base += 1024) {
    int i = base + tid;
    int x = (i < n) ? in[i] : 0;
    int incl = x;
#pragma unroll
    for (int off = 1; off < 64; off <<= 1) {
      int v = __shfl_up(incl, off);
      if (lane >= off) incl += v;
    }
    if (lane == 63) wbase[w] = incl;
    __syncthreads();
    if (w == 0) {
      int t = (lane < 16) ? wbase[lane] : 0;
      int it = t;
#pragma unroll
      for (int off = 1; off < 16; off <<= 1) {
        int v = __shfl_up(it, off);
        if (lane >= off) it += v;
      }
      if (lane < 16) wbase[lane] = it - t;
      if (lane == 15) chunk_tot = it;
    }
    __syncthreads();
    int excl = carry + wbase[w] + (incl - x);
    if (i < n) {
      out[i] = excl;
      if (cur) cur[i] = excl;
    }
    carry += chunk_tot;
    __syncthreads();
  }
  if (tid == 0) out[n] = carry;
}

__global__ void k_scatter(const int* __restrict__ src, const int* __restrict__ dst, int n,
                          int* __restrict__ cursor, int* __restrict__ dst_sorted) {
  int e = blockIdx.x * blockDim.x + threadIdx.x;
  if (e < n) {
    int s = src[e];
    int slot = atomicAdd(&cursor[s], 1);
    dst_sorted[slot] = dst[e];
  }
}

// ---------------- GEMM: OS[i][j] = sum_k U[i][k]*Wt[k][j] (+bias[j]) ----------------
// U: M x K (row stride ustride), Wt: K x 128 (padded, col 127 = 0), OS: M x 128
#define BM 32
#define BK 16
__global__ __launch_bounds__(256) void k_gemm(const float* __restrict__ U, int ustride, int K,
                                              const float* __restrict__ Wt,
                                              const float* __restrict__ bias,
                                              float* __restrict__ OS, int M) {
  __shared__ __align__(16) float UT[BK][36];
  __shared__ __align__(16) float WT[BK][128];
  int tid = threadIdx.x;
  int cg = tid & 31;  // cols cg*4 .. +3
  int rg = tid >> 5;  // rows rg*4 .. +3
  int base = blockIdx.x * BM;
  float acc[4][4] = {};
  for (int kk = 0; kk < K; kk += BK) {
// stage U tile (32 rows x 16 k), transposed into UT[k][row]
#pragma unroll
    for (int i = 0; i < 2; i++) {
      int f = tid + i * 256;
      int r = f >> 4;
      int k = f & 15;
      int row = base + r;
      float v = 0.f;
      if (row < M && (kk + k) < K) v = U[(size_t)row * ustride + kk + k];
      UT[k][r] = v;
    }
    // stage Wt tile (16 rows x 128), float4 coalesced
    {
      int k = tid >> 5;
      int j4 = (tid & 31) * 4;
#pragma unroll
      for (int i = 0; i < 2; i++) {
        int krow = k + i * 8;
        float4 v = make_float4(0.f, 0.f, 0.f, 0.f);
        if (kk + krow < K) v = *(const float4*)&Wt[(size_t)(kk + krow) * 128 + j4];
        *(float4*)&WT[krow][j4] = v;
      }
    }
    __syncthreads();
#pragma unroll
    for (int k = 0; k < BK; k++) {
      float4 wv = *(const float4*)&WT[k][cg * 4];
      float4 uv = *(const float4*)&UT[k][rg * 4];
      float uu[4] = {uv.x, uv.y, uv.z, uv.w};
      float ww[4] = {wv.x, wv.y, wv.z, wv.w};
#pragma unroll
      for (int r = 0; r < 4; r++)
#pragma unroll
        for (int c = 0; c < 4; c++) acc[r][c] += uu[r] * ww[c];
    }
    __syncthreads();
  }
  float bj[4];
#pragma unroll
  for (int c = 0; c < 4; c++) {
    int j = cg * 4 + c;
    bj[c] = (bias != nullptr && j < DD) ? bias[j] : 0.f;
  }
#pragma unroll
  for (int r = 0; r < 4; r++) {
    int row = base + rg * 4 + r;
    if (row < M) {
      float4 o = make_float4(acc[r][0] + bj[0], acc[r][1] + bj[1], acc[r][2] + bj[2],
                             acc[r][3] + bj[3]);
      *(float4*)&OS[(size_t)row * 128 + cg * 4] = o;
    }
  }
}

// ---------------- elementwise (wave per node) ----------------
// point = proj(expmap0([0, os]))   (os spatial k at col k, col 127 == 0)
__global__ void k_point_from_os(const float* __restrict__ OS, float* __restrict__ P,
                                const float* __restrict__ cptr, int n) {
  int node = blockIdx.x * 4 + (threadIdx.x >> 6);
  int lane = threadIdx.x & 63;
  if (node >= n) return;
  float c = *cptr;
  float sc = sqrtf(c);
  const float* os = OS + (size_t)node * 128;
  float u0 = os[lane], u1 = os[lane + 64];
  float nsq = wsum(u0 * u0 + u1 * u1);
  float nn = fmaxf(sqrtf(nsq), 1e-9f);
  float f = sc * sinhf(nn / sc) / nn;
  float t = sqrtf(c + f * f * nsq);
  float* p = P + (size_t)node * 128;
  float s0 = f * u0, s1 = f * u1;
  p[1 + lane] = s0;
  if (lane < 63) p[65 + lane] = s1;
  if (lane == 0) p[0] = t;
}

// tangent (GEMM layout): U[i][k] = logmap0(P)[k+1], k=0..126; U[i][127]=0
__global__ void k_tangent(const float* __restrict__ P, float* __restrict__ U,
                          const float* __restrict__ cptr, int n) {
  int node = blockIdx.x * 4 + (threadIdx.x >> 6);
  int lane = threadIdx.x & 63;
  if (node >= n) return;
  float c = *cptr;
  float sc = sqrtf(c);
  const float* p = P + (size_t)node * 128;
  float p0 = p[0];
  float y0 = p[1 + lane];
  float y1 = (lane < 63) ? p[65 + lane] : 0.f;
  float ynsq = wsum(y0 * y0 + y1 * y1);
  float yn = fmaxf(sqrtf(ynsq), 1e-9f);
  float d = sc * acoshf(fmaxf(p0 / sc, 1.f + EPSH));
  float s = d / yn;
  float* u = U + (size_t)node * 128;
  float o0 = s * y0, o1 = s * y1;
  u[lane] = o0;
  if (lane < 63)
    u[64 + lane] = o1;
  else
    u[127] = 0.f;
}

// out point = _hyp_act(_hyp_linear result): q=proj(expmap0([0,os])); vs=tanh(logmap0(q)); expmap0([0,vs])
__global__ void k_act_from_os(const float* __restrict__ OS, float* __restrict__ P,
                              const float* __restrict__ cptr, int n) {
  int node = blockIdx.x * 4 + (threadIdx.x >> 6);
  int lane = threadIdx.x & 63;
  if (node >= n) return;
  float c = *cptr;
  float sc = sqrtf(c);
  const float* os = OS + (size_t)node * 128;
  float u0 = os[lane], u1 = os[lane + 64];
  float n1sq = wsum(u0 * u0 + u1 * u1);
  float n1 = fmaxf(sqrtf(n1sq), 1e-9f);
  float f1 = sc * sinhf(n1 / sc) / n1;
  float qs0 = f1 * u0, qs1 = f1 * u1;
  float qssq = f1 * f1 * n1sq;
  float q0 = sqrtf(c + qssq);  // proj time component
  float yn = fmaxf(sqrtf(qssq), 1e-9f);
  float d = sc * acoshf(fmaxf(q0 / sc, 1.f + EPSH));
  float t0 = tanhf(d * qs0 / yn);
  float t1 = tanhf(d * qs1 / yn);
  float vsq = wsum(t0 * t0 + t1 * t1);
  float n2 = fmaxf(sqrtf(vsq), 1e-9f);
  float f2 = sc * sinhf(n2 / sc) / n2;
  float out0 = sc * coshf(n2 / sc);
  float* p = P + (size_t)node * 128;
  p[1 + lane] = f2 * t0;
  if (lane < 63) p[65 + lane] = f2 * t1;
  if (lane == 0) p[0] = out0;
}

// ---------------- aggregation: fused att + centroid + GIN combine ----------------
__global__ void k_aggregate(const float* __restrict__ H, const float* __restrict__ HL,
                            const int* __restrict__ rowp, const int* __restrict__ dsts,
                            const float* __restrict__ epsp, const float* __restrict__ cptr,
                            float* __restrict__ OUT, int n) {
  int node = blockIdx.x * 4 + (threadIdx.x >> 6);
  int lane = threadIdx.x & 63;
  if (node >= n) return;
  float c = *cptr;
  float sc = sqrtf(c);
  float eps = *epsp;
  float sgn0 = (lane == 0) ? -1.f : 1.f;
  const float* hli = HL + (size_t)node * 128;
  float a0 = hli[lane], a1 = hli[lane + 64];
  int e0 = rowp[node], e1 = rowp[node + 1];
  float m0 = 0.f, m1 = 0.f;
  for (int e = e0; e < e1; e++) {
    int d = dsts[e];
    const float* hld = HL + (size_t)d * 128;
    float b0 = hld[lane], b1 = hld[lane + 64];
    float inner = wsum(sgn0 * a0 * b0 + a1 * b1);
    float val = fmaxf(-inner / c, 1.f + EPSH);
    float att = expf(-sc * acoshf(val));
    const float* hd = H + (size_t)d * 128;
    m0 += att * hd[lane];
    m1 += att * hd[lane + 64];
  }
  // centroid
  float linner = wsum(sgn0 * m0 * m0 + m1 * m1);
  float denom = sqrtf(fmaxf(-linner, 1e-9f));
  float ct0 = sc * m0 / denom, ct1 = sc * m1 / denom;
  // proj(centroid)
  float ssq = wsum(((lane == 0) ? 0.f : ct0 * ct0) + ct1 * ct1);
  float agg0 = sqrtf(c + ssq);
  // logmap0(agg)
  float ynA = fmaxf(sqrtf(ssq), 1e-9f);
  float dA = sc * acoshf(fmaxf(agg0 / sc, 1.f + EPSH));
  float la0 = (lane == 0) ? 0.f : dA * ct0 / ynA;
  float la1 = dA * ct1 / ynA;
  // hp = proj(h); logmap0(hp)
  const float* hi = H + (size_t)node * 128;
  float h0 = hi[lane], h1 = hi[lane + 64];
  float hsq = wsum(((lane == 0) ? 0.f : h0 * h0) + h1 * h1);
  float hp0 = sqrtf(c + hsq);
  float ynH = fmaxf(sqrtf(hsq), 1e-9f);
  float dH = sc * acoshf(fmaxf(hp0 / sc, 1.f + EPSH));
  float lh0 = (lane == 0) ? 0.f : dH * h0 / ynH;
  float lh1 = dH * h1 / ynH;
  // v, out = proj(expmap0(v))
  float v0 = la0 + (1.f + eps) * lh0;
  float v1 = la1 + (1.f + eps) * lh1;
  float nsq = wsum(((lane == 0) ? 0.f : v0 * v0) + v1 * v1);
  float nv = fmaxf(sqrtf(nsq), 1e-9f);
  float f = sc * sinhf(nv / sc) / nv;
  float t = sqrtf(c + f * f * nsq);
  float* o = OUT + (size_t)node * 128;
  o[lane] = (lane == 0) ? t : f * v0;
  o[64 + lane] = f * v1;
}

// ---------------- pooling ----------------
__global__ void k_pool(const float* __restrict__ U, const int* __restrict__ gptr,
                       float* __restrict__ out, int layer) {
  int g = blockIdx.x;
  int c = threadIdx.x;  // 0..127
  int s = gptr[g], e = gptr[g + 1];
  float acc = 0.f;
  if (c > 0) {
    const float* up = U + (c - 1);
    int i = s;
    float a0 = 0.f, a1 = 0.f, a2 = 0.f, a3 = 0.f;
    for (; i + 3 < e; i += 4) {
      a0 += up[(size_t)i * 128];
      a1 += up[(size_t)(i + 1) * 128];
      a2 += up[(size_t)(i + 2) * 128];
      a3 += up[(size_t)(i + 3) * 128];
    }
    for (; i < e; i++) a0 += up[(size_t)i * 128];
    acc = (a0 + a1) + (a2 + a3);
  }
  out[(size_t)g * 256 + layer * 128 + c] = acc;
}

// ---------------- launch ----------------
extern "C" void kernel_launch(void* const* d_in, const int* in_sizes, int n_in, void* d_out,
                              int out_size, void* d_ws, size_t ws_size, hipStream_t stream) {
  const float* x = (const float*)d_in[0];
  const float* cptr = (const float*)d_in[1];
  const float* w_in = (const float*)d_in[2];
  const float* att_w = (const float*)d_in[3];
  const float* att_b = (const float*)d_in[4];
  const float* epsv = (const float*)d_in[5];
  const float* mlp_w = (const float*)d_in[6];
  const float* mlp_b = (const float*)d_in[7];
  const int* ei = (const int*)d_in[8];
  const int* batch = (const int*)d_in[9];
  const int* srcp = ei;
  const int* dstp = ei + EE;
  float* out = (float*)d_out;

  float* ws = (float*)d_ws;
  float* Wt = ws;                 // 6*16384
  float* winp = Wt + 6 * 16384;   // 200*128
  int* deg = (int*)(winp + IN_F * 128);  // N
  int* gcnt = deg + NN;                  // G (contiguous with deg for one memset)
  int* rowp = gcnt + GG;                 // N+1
  int* cursor = rowp + NN + 1;           // N
  int* gptr = cursor + NN;               // G+1
  int* dsts = gptr + GG + 1;             // E
  size_t a_off = (size_t)((dsts + EE) - (int*)ws);
  a_off = (a_off + 3) & ~(size_t)3;  // 16B align
  float* A = ws + a_off;
  float* B = A + (size_t)NN * 128;
  float* C = B + (size_t)NN * 128;

  const int EW = 12500;  // elementwise grid (4 nodes/block)
  const int GEMMG = (NN + BM - 1) / BM;

  hipMemsetAsync(deg, 0, (NN + GG) * sizeof(int), stream);
  k_prep_w<<<7, 256, 0, stream>>>(att_w, mlp_w, w_in, Wt, winp);
  k_count<<<(EE + 255) / 256, 256, 0, stream>>>(srcp, EE, deg);
  k_count<<<(NN + 255) / 256, 256, 0, stream>>>(batch, NN, gcnt);
  k_scan_excl<<<1, 1024, 0, stream>>>(deg, NN, rowp, cursor);
  k_scan_excl<<<1, 1024, 0, stream>>>(gcnt, GG, gptr, nullptr);
  k_scatter<<<(EE + 255) / 256, 256, 0, stream>>>(srcp, dstp, EE, cursor, dsts);

  // input: os = x @ w_in ; h = proj(expmap0([0,os]))  -> A
  k_gemm<<<GEMMG, 256, 0, stream>>>(x, IN_F, IN_F, winp, nullptr, A, NN);
  k_point_from_os<<<EW, 256, 0, stream>>>(A, A, cptr, NN);

  // ---- layer 0 (H = A) ----
  k_tangent<<<EW, 256, 0, stream>>>(A, C, cptr, NN);
  k_gemm<<<GEMMG, 256, 0, stream>>>(C, 128, 128, Wt + 0 * 16384, att_b + 0 * DD, C, NN);
  k_point_from_os<<<EW, 256, 0, stream>>>(C, C, cptr, NN);  // HL = C
  k_aggregate<<<EW, 256, 0, stream>>>(A, C, rowp, dsts, epsv + 0, cptr, B, NN);
  k_tangent<<<EW, 256, 0, stream>>>(B, B, cptr, NN);
  k_gemm<<<GEMMG, 256, 0, stream>>>(B, 128, 128, Wt + 2 * 16384, mlp_b + 0 * DD, B, NN);
  k_act_from_os<<<EW, 256, 0, stream>>>(B, B, cptr, NN);
  k_tangent<<<EW, 256, 0, stream>>>(B, B, cptr, NN);
  k_gemm<<<GEMMG, 256, 0, stream>>>(B, 128, 128, Wt + 3 * 16384, mlp_b + 1 * DD, B, NN);
  k_act_from_os<<<EW, 256, 0, stream>>>(B, B, cptr, NN);  // layer0 output point -> B
  k_tangent<<<EW, 256, 0, stream>>>(B, A, cptr, NN);      // tangent(out0) -> A
  k_pool<<<GG, 128, 0, stream>>>(A, gptr, out, 0);

  // ---- layer 1 (H = B, tangent already in A) ----
  k_gemm<<<GEMMG, 256, 0, stream>>>(A, 128, 128, Wt + 1 * 16384, att_b + 1 * DD, A, NN);
  k_point_from_os<<<EW, 256, 0, stream>>>(A, A, cptr, NN);  // HL = A
  k_aggregate<<<EW, 256, 0, stream>>>(B, A, rowp, dsts, epsv + 1, cptr, C, NN);
  k_tangent<<<EW, 256, 0, stream>>>(C, C, cptr, NN);
  k_gemm<<<GEMMG, 256, 0, stream>>>(C, 128, 128, Wt + 4 * 16384, mlp_b + 2 * DD, C, NN);
  k_act_from_os<<<EW, 256, 0, stream>>>(C, C, cptr, NN);
  k_tangent<<<EW, 256, 0, stream>>>(C, C, cptr, NN);
  k_gemm<<<GEMMG, 256, 0, stream>>>(C, 128, 128, Wt + 5 * 16384, mlp_b + 3 * DD, C, NN);
  k_act_from_os<<<EW, 256, 0, stream>>>(C, C, cptr, NN);  // layer1 output point -> C
  k_tangent<<<EW, 256, 0, stream>>>(C, A, cptr, NN);
  k_pool<<<GG, 128, 0, stream>>>(A, gptr, out, 1);
}

// Round 2
// 912.257 us; speedup vs baseline: 1.6123x; 1.6123x over previous
//
#include <hip/hip_runtime.h>
#include <math.h>

#define NN 50000
#define EE 800000
#define IN_F 200
#define DD 127
#define GG 512
#define EPSH 1e-5f

__device__ __forceinline__ float wsum(float v) {
#pragma unroll
  for (int off = 32; off > 0; off >>= 1) v += __shfl_xor(v, off);
  return v;
}

__device__ __forceinline__ float hsum32(float v) {
#pragma unroll
  for (int off = 16; off > 0; off >>= 1) v += __shfl_xor(v, off);
  return v;
}

// ---------------- prep: transpose weights, pad w_in ----------------
__global__ void k_prep_w(const float* __restrict__ att_w, const float* __restrict__ mlp_w,
                         const float* __restrict__ w_in, float* __restrict__ Wt,
                         float* __restrict__ winp) {
  int b = blockIdx.x, tid = threadIdx.x;
  if (b < 6) {
    const float* src = (b < 2) ? att_w + b * DD * DD : mlp_w + (b - 2) * DD * DD;
    float* dst = Wt + b * 16384;
    for (int f = tid; f < 16384; f += 256) {
      int k = f >> 7, j = f & 127;
      dst[f] = (k < DD && j < DD) ? src[j * DD + k] : 0.f;
    }
  } else {
    for (int f = tid; f < IN_F * 128; f += 256) {
      int k = f >> 7, j = f & 127;
      winp[f] = (j < DD) ? w_in[k * DD + j] : 0.f;
    }
  }
}

// ---------------- CSR build ----------------
__global__ void k_count(const int* __restrict__ idx, int n, int* __restrict__ cnt) {
  int i = blockIdx.x * blockDim.x + threadIdx.x;
  if (i < n) atomicAdd(&cnt[idx[i]], 1);
}

__global__ __launch_bounds__(1024) void k_scan_excl(const int* __restrict__ in, int n,
                                                    int* __restrict__ out, int* __restrict__ cur) {
  __shared__ int wbase[16];
  __shared__ int chunk_tot;
  int tid = threadIdx.x;
  int lane = tid & 63;
  int w = tid >> 6;
  int carry = 0;
  for (int base = 0; base < n; base += 1024) {
    int i = base + tid;
    int x = (i < n) ? in[i] : 0;
    int incl = x;
#pragma unroll
    for (int off = 1; off < 64; off <<= 1) {
      int v = __shfl_up(incl, off);
      if (lane >= off) incl += v;
    }
    if (lane == 63) wbase[w] = incl;
    __syncthreads();
    if (w == 0) {
      int t = (lane < 16) ? wbase[lane] : 0;
      int it = t;
#pragma unroll
      for (int off = 1; off < 16; off <<= 1) {
        int v = __shfl_up(it, off);
        if (lane >= off) it += v;
      }
      if (lane < 16) wbase[lane] = it - t;
      if (lane == 15) chunk_tot = it;
    }
    __syncthreads();
    int excl = carry + wbase[w] + (incl - x);
    if (i < n) {
      out[i] = excl;
      if (cur) cur[i] = excl;
    }
    carry += chunk_tot;
    __syncthreads();
  }
  if (tid == 0) out[n] = carry;
}

__global__ void k_scatter(const int* __restrict__ src, const int* __restrict__ dst, int n,
                          int* __restrict__ cursor, int* __restrict__ src_sorted,
                          int* __restrict__ dst_sorted) {
  int e = blockIdx.x * blockDim.x + threadIdx.x;
  if (e < n) {
    int s = src[e];
    int slot = atomicAdd(&cursor[s], 1);
    src_sorted[slot] = s;
    dst_sorted[slot] = dst[e];
  }
}

// ---------------- fused GEMM + epilogue ----------------
// OS[i][j] = sum_k U[i][k]*Wt[k][j] + bias[j]
// MODE bits: 1=tanh, 2=store tangent T, 4=store point (PS spatial cols 0..126 + PT time)
#define BM 32
#define BK 16
#define MF_TANH 1
#define MF_T 2
#define MF_P 4

template <int MODE>
__global__ __launch_bounds__(256) void k_gemm2(const float* __restrict__ U, int ustride, int K,
                                               const float* __restrict__ Wt,
                                               const float* __restrict__ bias,
                                               float* __restrict__ T_out,
                                               float* __restrict__ PS_out,
                                               float* __restrict__ PT_out,
                                               const float* __restrict__ cptr, int M) {
  __shared__ __align__(16) float UT[BK][36];
  __shared__ __align__(16) float WT[BK][128];
  int tid = threadIdx.x;
  int cg = tid & 31;
  int rg = tid >> 5;
  int base = blockIdx.x * BM;
  float acc[4][4] = {};
  for (int kk = 0; kk < K; kk += BK) {
#pragma unroll
    for (int i = 0; i < 2; i++) {
      int f = tid + i * 256;
      int r = f >> 4;
      int k = f & 15;
      int row = base + r;
      float v = 0.f;
      if (row < M && (kk + k) < K) v = U[(size_t)row * ustride + kk + k];
      UT[k][r] = v;
    }
    {
      int k = tid >> 5;
      int j4 = (tid & 31) * 4;
#pragma unroll
      for (int i = 0; i < 2; i++) {
        int krow = k + i * 8;
        float4 v = make_float4(0.f, 0.f, 0.f, 0.f);
        if (kk + krow < K) v = *(const float4*)&Wt[(size_t)(kk + krow) * 128 + j4];
        *(float4*)&WT[krow][j4] = v;
      }
    }
    __syncthreads();
#pragma unroll
    for (int k = 0; k < BK; k++) {
      float4 wv = *(const float4*)&WT[k][cg * 4];
      float4 uv = *(const float4*)&UT[k][rg * 4];
      float uu[4] = {uv.x, uv.y, uv.z, uv.w};
      float ww[4] = {wv.x, wv.y, wv.z, wv.w};
#pragma unroll
      for (int r = 0; r < 4; r++)
#pragma unroll
        for (int c = 0; c < 4; c++) acc[r][c] += uu[r] * ww[c];
    }
    __syncthreads();
  }
  float bj[4];
#pragma unroll
  for (int c = 0; c < 4; c++) {
    int j = cg * 4 + c;
    bj[c] = (bias != nullptr && j < DD) ? bias[j] : 0.f;
  }
  float cc = 1.f, sc = 1.f;
  if (MODE & MF_P) {
    cc = *cptr;
    sc = sqrtf(cc);
  }
#pragma unroll
  for (int r = 0; r < 4; r++) {
    int row = base + rg * 4 + r;
    float vs[4];
#pragma unroll
    for (int c = 0; c < 4; c++) {
      float v = acc[r][c] + bj[c];
      if (MODE & MF_TANH) v = tanhf(v);
      vs[c] = v;
    }
    if ((MODE & MF_T) && row < M) {
      float4 o = make_float4(vs[0], vs[1], vs[2], vs[3]);
      *(float4*)&T_out[(size_t)row * 128 + cg * 4] = o;
    }
    if (MODE & MF_P) {
      float psq = vs[0] * vs[0] + vs[1] * vs[1] + vs[2] * vs[2] + vs[3] * vs[3];
      float nsq = hsum32(psq);
      float nn = fmaxf(sqrtf(nsq), 1e-9f);
      float e = expf(nn / sc);
      float ei = 1.f / e;
      float f = sc * (e - ei) * 0.5f / nn;
      float t = sqrtf(cc + f * f * nsq);
      if (row < M) {
        float4 o = make_float4(f * vs[0], f * vs[1], f * vs[2], f * vs[3]);
        *(float4*)&PS_out[(size_t)row * 128 + cg * 4] = o;
        if (cg == 0) PT_out[row] = t;
      }
    }
  }
}

// ---------------- attention: wave handles 64 sorted edges ----------------
__global__ __launch_bounds__(256) void k_att(const float* __restrict__ PS,
                                             const float* __restrict__ PT,
                                             const int* __restrict__ srcs,
                                             const int* __restrict__ dsts,
                                             const float* __restrict__ cptr,
                                             float* __restrict__ att) {
  int lane = threadIdx.x & 63;
  int base = (blockIdx.x * 4 + (threadIdx.x >> 6)) * 64;
  float c = *cptr, sc = sqrtf(c);
  float rcpc = 1.f / c;
  int s_l = srcs[base + lane];
  int d_l = dsts[base + lane];
  float myinner = 0.f;
  int sprev = -1;
  float a0 = 0.f, a1 = 0.f;
  for (int i = 0; i < 64; i++) {
    int s = __shfl(s_l, i);
    int d = __shfl(d_l, i);
    if (s != sprev) {
      const float* ps = PS + (size_t)s * 128;
      a0 = ps[lane];
      a1 = ps[lane + 64];
      sprev = s;
    }
    const float* pd = PS + (size_t)d * 128;
    float p = a0 * pd[lane] + a1 * pd[lane + 64];
    float red = wsum(p);
    if (lane == i) myinner = red;
  }
  float inner = myinner - PT[s_l] * PT[d_l];
  float val = fmaxf(-inner * rcpc, 1.f + EPSH);
  float w = val + sqrtf(val * val - 1.f);
  att[base + lane] = exp2f(-sc * __log2f(w));  // exp(-sc*acosh(val))
}

// ---------------- aggregation: att-weighted centroid + GIN combine (tangent out) ----------------
__global__ void k_agg(const float* __restrict__ PS_H, const float* __restrict__ PT_H,
                      const float* __restrict__ T, const int* __restrict__ rowp,
                      const int* __restrict__ dsts, const float* __restrict__ att,
                      const float* __restrict__ epsp, const float* __restrict__ cptr,
                      float* __restrict__ Tout, int n) {
  int node = blockIdx.x * 4 + (threadIdx.x >> 6);
  int lane = threadIdx.x & 63;
  if (node >= n) return;
  float c = *cptr, sc = sqrtf(c);
  float eps = *epsp;
  int e0 = rowp[node], e1 = rowp[node + 1];
  float m0 = 0.f, m1 = 0.f, mt = 0.f;
  for (int e = e0; e < e1; e++) {
    int d = dsts[e];
    float a = att[e];
    const float* ps = PS_H + (size_t)d * 128;
    m0 += a * ps[lane];
    m1 += a * ps[lane + 64];
    mt += a * PT_H[d];
  }
  float lsq = wsum(m0 * m0 + m1 * m1);
  float neg_inner = mt * mt - lsq;  // -l_inner(m,m)
  float denom = sqrtf(fmaxf(neg_inner, 1e-9f));
  float r = sc / denom;
  float ssq = r * r * lsq;               // ||proj(centroid) spatial||^2
  float agg0 = sqrtf(c + ssq);           // proj time
  float ynA = fmaxf(sqrtf(ssq), 1e-9f);
  float v2 = fmaxf(agg0 / sc, 1.f + EPSH);
  float dA = sc * 0.69314718056f * __log2f(v2 + sqrtf(v2 * v2 - 1.f));  // sc*acosh
  float sca = dA * r / ynA;
  const float* t = T + (size_t)node * 128;
  float v0 = sca * m0 + (1.f + eps) * t[lane];
  float v1 = sca * m1 + (1.f + eps) * t[lane + 64];
  float* o = Tout + (size_t)node * 128;
  o[lane] = v0;
  o[64 + lane] = v1;  // col127 stays 0 (m1[63]=0, t[127]=0)
}

// ---------------- pooling ----------------
__global__ void k_pool(const float* __restrict__ U, const int* __restrict__ gptr,
                       float* __restrict__ out, int layer) {
  int g = blockIdx.x;
  int c = threadIdx.x;  // 0..127
  int s = gptr[g], e = gptr[g + 1];
  float acc = 0.f;
  if (c > 0) {
    const float* up = U + (c - 1);
    int i = s;
    float a0 = 0.f, a1 = 0.f, a2 = 0.f, a3 = 0.f;
    for (; i + 3 < e; i += 4) {
      a0 += up[(size_t)i * 128];
      a1 += up[(size_t)(i + 1) * 128];
      a2 += up[(size_t)(i + 2) * 128];
      a3 += up[(size_t)(i + 3) * 128];
    }
    for (; i < e; i++) a0 += up[(size_t)i * 128];
    acc = (a0 + a1) + (a2 + a3);
  }
  out[(size_t)g * 256 + layer * 128 + c] = acc;
}

// ---------------- launch ----------------
extern "C" void kernel_launch(void* const* d_in, const int* in_sizes, int n_in, void* d_out,
                              int out_size, void* d_ws, size_t ws_size, hipStream_t stream) {
  const float* x = (const float*)d_in[0];
  const float* cptr = (const float*)d_in[1];
  const float* w_in = (const float*)d_in[2];
  const float* att_w = (const float*)d_in[3];
  const float* att_b = (const float*)d_in[4];
  const float* epsv = (const float*)d_in[5];
  const float* mlp_w = (const float*)d_in[6];
  const float* mlp_b = (const float*)d_in[7];
  const int* ei = (const int*)d_in[8];
  const int* batch = (const int*)d_in[9];
  const int* srcp = ei;
  const int* dstp = ei + EE;
  float* out = (float*)d_out;

  float* ws = (float*)d_ws;
  float* Wt = ws;                        // 6*16384
  float* winp = Wt + 6 * 16384;          // 200*128
  int* deg = (int*)(winp + IN_F * 128);  // N
  int* gcnt = deg + NN;                  // G
  int* rowp = gcnt + GG;                 // N+1
  int* cursor = rowp + NN + 1;           // N
  int* gptr = cursor + NN;               // G+1
  int* srcs = gptr + GG + 1;             // E
  int* dsts = srcs + EE;                 // E
  float* att = (float*)(dsts + EE);      // E
  float* pt1 = att + EE;                 // N
  float* pt2 = pt1 + NN;                 // N
  size_t a_off = (size_t)((pt2 + NN) - ws);
  a_off = (a_off + 3) & ~(size_t)3;
  float* A = ws + a_off;
  float* B = A + (size_t)NN * 128;
  float* C = B + (size_t)NN * 128;

  const int EW = 12500;
  const int GEMMG = (NN + BM - 1) / BM;
  const int ATTG = EE / 256;  // 3125 blocks, 4 waves x 64 edges

  hipMemsetAsync(deg, 0, (NN + GG) * sizeof(int), stream);
  k_prep_w<<<7, 256, 0, stream>>>(att_w, mlp_w, w_in, Wt, winp);
  k_count<<<(EE + 255) / 256, 256, 0, stream>>>(srcp, EE, deg);
  k_count<<<(NN + 255) / 256, 256, 0, stream>>>(batch, NN, gcnt);
  k_scan_excl<<<1, 1024, 0, stream>>>(deg, NN, rowp, cursor);
  k_scan_excl<<<1, 1024, 0, stream>>>(gcnt, GG, gptr, nullptr);
  k_scatter<<<(EE + 255) / 256, 256, 0, stream>>>(srcp, dstp, EE, cursor, srcs, dsts);

  // input: T0 = x@w_in -> A ; H point -> (B, pt1)
  k_gemm2<MF_T | MF_P><<<GEMMG, 256, 0, stream>>>(x, IN_F, IN_F, winp, nullptr, A, B, pt1, cptr, NN);

  // ---- layer 0 ----
  k_gemm2<MF_P><<<GEMMG, 256, 0, stream>>>(A, 128, 128, Wt + 0 * 16384, att_b + 0 * DD, nullptr, C, pt2, cptr, NN);
  k_att<<<ATTG, 256, 0, stream>>>(C, pt2, srcs, dsts, cptr, att);
  k_agg<<<EW, 256, 0, stream>>>(B, pt1, A, rowp, dsts, att, epsv + 0, cptr, C, NN);
  k_gemm2<MF_TANH | MF_T><<<GEMMG, 256, 0, stream>>>(C, 128, 128, Wt + 2 * 16384, mlp_b + 0 * DD, A, nullptr, nullptr, cptr, NN);
  k_gemm2<MF_TANH | MF_T | MF_P><<<GEMMG, 256, 0, stream>>>(A, 128, 128, Wt + 3 * 16384, mlp_b + 1 * DD, C, B, pt1, cptr, NN);
  k_pool<<<GG, 128, 0, stream>>>(C, gptr, out, 0);

  // ---- layer 1 ----
  k_gemm2<MF_P><<<GEMMG, 256, 0, stream>>>(C, 128, 128, Wt + 1 * 16384, att_b + 1 * DD, nullptr, A, pt2, cptr, NN);
  k_att<<<ATTG, 256, 0, stream>>>(A, pt2, srcs, dsts, cptr, att);
  k_agg<<<EW, 256, 0, stream>>>(B, pt1, C, rowp, dsts, att, epsv + 1, cptr, A, NN);
  k_gemm2<MF_TANH | MF_T><<<GEMMG, 256, 0, stream>>>(A, 128, 128, Wt + 4 * 16384, mlp_b + 2 * DD, C, nullptr, nullptr, cptr, NN);
  k_gemm2<MF_TANH | MF_T><<<GEMMG, 256, 0, stream>>>(C, 128, 128, Wt + 5 * 16384, mlp_b + 3 * DD, A, nullptr, nullptr, cptr, NN);
  k_pool<<<GG, 128, 0, stream>>>(A, gptr, out, 1);
}

// Round 3
// 847.512 us; speedup vs baseline: 1.7354x; 1.0764x over previous
//
#include <hip/hip_runtime.h>
#include <math.h>

#define NN 50000
#define EE 800000
#define IN_F 200
#define DD 127
#define GG 512
#define EPSH 1e-5f

typedef unsigned int u32;

__device__ __forceinline__ float wsum(float v) {
#pragma unroll
  for (int off = 32; off > 0; off >>= 1) v += __shfl_xor(v, off);
  return v;
}

__device__ __forceinline__ float hsum32(float v) {
#pragma unroll
  for (int off = 16; off > 0; off >>= 1) v += __shfl_xor(v, off);
  return v;
}

__device__ __forceinline__ u32 bf16r(float x) {  // round-to-nearest-even bf16 bits
  u32 u = __float_as_uint(x);
  return (u + 0x7fffu + ((u >> 16) & 1u)) >> 16;
}

// ---------------- prep: transpose weights, pad w_in ----------------
__global__ void k_prep_w(const float* __restrict__ att_w, const float* __restrict__ mlp_w,
                         const float* __restrict__ w_in, float* __restrict__ Wt,
                         float* __restrict__ winp) {
  int b = blockIdx.x, tid = threadIdx.x;
  if (b < 6) {
    const float* src = (b < 2) ? att_w + b * DD * DD : mlp_w + (b - 2) * DD * DD;
    float* dst = Wt + b * 16384;
    for (int f = tid; f < 16384; f += 256) {
      int k = f >> 7, j = f & 127;
      dst[f] = (k < DD && j < DD) ? src[j * DD + k] : 0.f;
    }
  } else {
    for (int f = tid; f < IN_F * 128; f += 256) {
      int k = f >> 7, j = f & 127;
      winp[f] = (j < DD) ? w_in[k * DD + j] : 0.f;
    }
  }
}

// ---------------- CSR build ----------------
__global__ void k_count(const int* __restrict__ idx, int n, int* __restrict__ cnt) {
  int i = blockIdx.x * blockDim.x + threadIdx.x;
  if (i < n) atomicAdd(&cnt[idx[i]], 1);
}

__global__ __launch_bounds__(1024) void k_scan_excl(const int* __restrict__ in, int n,
                                                    int* __restrict__ out, int* __restrict__ cur) {
  __shared__ int wbase[16];
  __shared__ int chunk_tot;
  int tid = threadIdx.x;
  int lane = tid & 63;
  int w = tid >> 6;
  int carry = 0;
  for (int base = 0; base < n; base += 1024) {
    int i = base + tid;
    int x = (i < n) ? in[i] : 0;
    int incl = x;
#pragma unroll
    for (int off = 1; off < 64; off <<= 1) {
      int v = __shfl_up(incl, off);
      if (lane >= off) incl += v;
    }
    if (lane == 63) wbase[w] = incl;
    __syncthreads();
    if (w == 0) {
      int t = (lane < 16) ? wbase[lane] : 0;
      int it = t;
#pragma unroll
      for (int off = 1; off < 16; off <<= 1) {
        int v = __shfl_up(it, off);
        if (lane >= off) it += v;
      }
      if (lane < 16) wbase[lane] = it - t;
      if (lane == 15) chunk_tot = it;
    }
    __syncthreads();
    int excl = carry + wbase[w] + (incl - x);
    if (i < n) {
      out[i] = excl;
      if (cur) cur[i] = excl;
    }
    carry += chunk_tot;
    __syncthreads();
  }
  if (tid == 0) out[n] = carry;
}

__global__ void k_scatter(const int* __restrict__ src, const int* __restrict__ dst, int n,
                          int* __restrict__ cursor, int* __restrict__ dst_sorted) {
  int e = blockIdx.x * blockDim.x + threadIdx.x;
  if (e < n) {
    int s = src[e];
    int slot = atomicAdd(&cursor[s], 1);
    dst_sorted[slot] = dst[e];
  }
}

// ---------------- fused GEMM + epilogue ----------------
// OS[i][j] = sum_k U[i][k]*Wt[k][j] + bias[j]
// MODE bits: 1=tanh, 2=store fp32 tangent T, 4=store bf16 point rows (PSb) + fp32 time (PT)
#define BM 32
#define BK 16
#define MF_TANH 1
#define MF_T 2
#define MF_P 4

template <int MODE>
__global__ __launch_bounds__(256) void k_gemm2(const float* __restrict__ U, int ustride, int K,
                                               const float* __restrict__ Wt,
                                               const float* __restrict__ bias,
                                               float* __restrict__ T_out,
                                               u32* __restrict__ PSb_out,
                                               float* __restrict__ PT_out,
                                               const float* __restrict__ cptr, int M) {
  __shared__ __align__(16) float UT[BK][36];
  __shared__ __align__(16) float WT[BK][128];
  int tid = threadIdx.x;
  int cg = tid & 31;
  int rg = tid >> 5;
  int base = blockIdx.x * BM;
  float acc[4][4] = {};
  for (int kk = 0; kk < K; kk += BK) {
#pragma unroll
    for (int i = 0; i < 2; i++) {
      int f = tid + i * 256;
      int r = f >> 4;
      int k = f & 15;
      int row = base + r;
      float v = 0.f;
      if (row < M && (kk + k) < K) v = U[(size_t)row * ustride + kk + k];
      UT[k][r] = v;
    }
    {
      int k = tid >> 5;
      int j4 = (tid & 31) * 4;
#pragma unroll
      for (int i = 0; i < 2; i++) {
        int krow = k + i * 8;
        float4 v = make_float4(0.f, 0.f, 0.f, 0.f);
        if (kk + krow < K) v = *(const float4*)&Wt[(size_t)(kk + krow) * 128 + j4];
        *(float4*)&WT[krow][j4] = v;
      }
    }
    __syncthreads();
#pragma unroll
    for (int k = 0; k < BK; k++) {
      float4 wv = *(const float4*)&WT[k][cg * 4];
      float4 uv = *(const float4*)&UT[k][rg * 4];
      float uu[4] = {uv.x, uv.y, uv.z, uv.w};
      float ww[4] = {wv.x, wv.y, wv.z, wv.w};
#pragma unroll
      for (int r = 0; r < 4; r++)
#pragma unroll
        for (int c = 0; c < 4; c++) acc[r][c] += uu[r] * ww[c];
    }
    __syncthreads();
  }
  float bj[4];
#pragma unroll
  for (int c = 0; c < 4; c++) {
    int j = cg * 4 + c;
    bj[c] = (bias != nullptr && j < DD) ? bias[j] : 0.f;
  }
  float cc = 1.f, sc = 1.f;
  if (MODE & MF_P) {
    cc = *cptr;
    sc = sqrtf(cc);
  }
#pragma unroll
  for (int r = 0; r < 4; r++) {
    int row = base + rg * 4 + r;
    float vs[4];
#pragma unroll
    for (int c = 0; c < 4; c++) {
      float v = acc[r][c] + bj[c];
      if (MODE & MF_TANH) v = tanhf(v);
      vs[c] = v;
    }
    if ((MODE & MF_T) && row < M) {
      float4 o = make_float4(vs[0], vs[1], vs[2], vs[3]);
      *(float4*)&T_out[(size_t)row * 128 + cg * 4] = o;
    }
    if (MODE & MF_P) {
      float psq = vs[0] * vs[0] + vs[1] * vs[1] + vs[2] * vs[2] + vs[3] * vs[3];
      float nsq = hsum32(psq);
      float nn = fmaxf(sqrtf(nsq), 1e-9f);
      float e = expf(nn / sc);
      float ei = 1.f / e;
      float f = sc * (e - ei) * 0.5f / nn;
      float t = sqrtf(cc + f * f * nsq);
      if (row < M) {
        uint2 o;
        o.x = bf16r(f * vs[0]) | (bf16r(f * vs[1]) << 16);
        o.y = bf16r(f * vs[2]) | (bf16r(f * vs[3]) << 16);
        *(uint2*)&PSb_out[(size_t)row * 64 + cg * 2] = o;
        if (cg == 0) PT_out[row] = t;
      }
    }
  }
}

// ---------------- fused attention + aggregation + GIN combine ----------------
// Point rows bf16-packed: row = 64 u32, u32[l] = cols {2l (lo), 2l+1 (hi)}, col127 = 0.
__global__ void k_agg_f(const u32* __restrict__ Hb, const float* __restrict__ ptH,
                        const u32* __restrict__ HLb, const float* __restrict__ ptHL,
                        const float* __restrict__ T, const int* __restrict__ rowp,
                        const int* __restrict__ dsts, const float* __restrict__ epsp,
                        const float* __restrict__ cptr, float* __restrict__ Tout, int n) {
  int node = blockIdx.x * 4 + (threadIdx.x >> 6);
  int lane = threadIdx.x & 63;
  if (node >= n) return;
  float c = *cptr, sc = sqrtf(c), rcpc = 1.f / c;
  float eps = *epsp;
  u32 au = HLb[(size_t)node * 64 + lane];
  float a0 = __uint_as_float(au << 16);
  float a1 = __uint_as_float(au & 0xffff0000u);
  float pts = ptHL[node];
  int e0 = rowp[node], e1 = rowp[node + 1];
  float m0 = 0.f, m1 = 0.f, mt = 0.f;
  for (int e = e0; e < e1; e++) {
    int d = dsts[e];
    u32 bu = HLb[(size_t)d * 64 + lane];
    u32 hu = Hb[(size_t)d * 64 + lane];
    float ptd = ptHL[d];
    float pth = ptH[d];
    float b0 = __uint_as_float(bu << 16);
    float b1 = __uint_as_float(bu & 0xffff0000u);
    float sp = wsum(a0 * b0 + a1 * b1);
    float val = fmaxf((pts * ptd - sp) * rcpc, 1.f + EPSH);
    float w = val + sqrtf(val * val - 1.f);
    float att = exp2f(-sc * __log2f(w));  // exp(-sc*acosh(val))
    float h0 = __uint_as_float(hu << 16);
    float h1 = __uint_as_float(hu & 0xffff0000u);
    m0 = fmaf(att, h0, m0);
    m1 = fmaf(att, h1, m1);
    mt = fmaf(att, pth, mt);
  }
  float lsq = wsum(m0 * m0 + m1 * m1);
  float neg_inner = mt * mt - lsq;  // -l_inner(m,m)
  float denom = sqrtf(fmaxf(neg_inner, 1e-9f));
  float r = sc / denom;
  float ssq = r * r * lsq;
  float agg0 = sqrtf(c + ssq);
  float ynA = fmaxf(sqrtf(ssq), 1e-9f);
  float v2 = fmaxf(agg0 / sc, 1.f + EPSH);
  float dA = sc * 0.69314718056f * __log2f(v2 + sqrtf(v2 * v2 - 1.f));  // sc*acosh
  float sca = dA * r / ynA;
  const float2 tv = *(const float2*)&T[(size_t)node * 128 + lane * 2];
  float2 o = make_float2(sca * m0 + (1.f + eps) * tv.x, sca * m1 + (1.f + eps) * tv.y);
  *(float2*)&Tout[(size_t)node * 128 + lane * 2] = o;
}

// ---------------- pooling ----------------
__global__ void k_pool(const float* __restrict__ U, const int* __restrict__ gptr,
                       float* __restrict__ out, int layer) {
  int g = blockIdx.x;
  int c = threadIdx.x;  // 0..127
  int s = gptr[g], e = gptr[g + 1];
  float acc = 0.f;
  if (c > 0) {
    const float* up = U + (c - 1);
    int i = s;
    float a0 = 0.f, a1 = 0.f, a2 = 0.f, a3 = 0.f;
    for (; i + 3 < e; i += 4) {
      a0 += up[(size_t)i * 128];
      a1 += up[(size_t)(i + 1) * 128];
      a2 += up[(size_t)(i + 2) * 128];
      a3 += up[(size_t)(i + 3) * 128];
    }
    for (; i < e; i++) a0 += up[(size_t)i * 128];
    acc = (a0 + a1) + (a2 + a3);
  }
  out[(size_t)g * 256 + layer * 128 + c] = acc;
}

// ---------------- launch ----------------
extern "C" void kernel_launch(void* const* d_in, const int* in_sizes, int n_in, void* d_out,
                              int out_size, void* d_ws, size_t ws_size, hipStream_t stream) {
  const float* x = (const float*)d_in[0];
  const float* cptr = (const float*)d_in[1];
  const float* w_in = (const float*)d_in[2];
  const float* att_w = (const float*)d_in[3];
  const float* att_b = (const float*)d_in[4];
  const float* epsv = (const float*)d_in[5];
  const float* mlp_w = (const float*)d_in[6];
  const float* mlp_b = (const float*)d_in[7];
  const int* ei = (const int*)d_in[8];
  const int* batch = (const int*)d_in[9];
  const int* srcp = ei;
  const int* dstp = ei + EE;
  float* out = (float*)d_out;

  float* ws = (float*)d_ws;
  float* Wt = ws;                        // 6*16384
  float* winp = Wt + 6 * 16384;          // 200*128
  int* deg = (int*)(winp + IN_F * 128);  // N
  int* gcnt = deg + NN;                  // G (contiguous with deg: one memset)
  int* rowp = gcnt + GG;                 // N+1
  int* cursor = rowp + NN + 1;           // N
  int* gptr = cursor + NN;               // G+1
  int* dsts = gptr + GG + 1;             // E
  float* ptH = (float*)(dsts + EE);      // N
  float* ptHL = ptH + NN;                // N
  size_t off = (size_t)((ptHL + NN) - ws);
  off = (off + 3) & ~(size_t)3;
  u32* Hb = (u32*)(ws + off);            // N*64 u32 (bf16-packed point rows)
  u32* HLb = Hb + (size_t)NN * 64;       // N*64
  float* A = (float*)(HLb + (size_t)NN * 64);  // N*128 fp32
  float* B = A + (size_t)NN * 128;             // N*128 fp32

  const int EW = 12500;  // 4 nodes/block
  const int GEMMG = (NN + BM - 1) / BM;

  hipMemsetAsync(deg, 0, (NN + GG) * sizeof(int), stream);
  k_prep_w<<<7, 256, 0, stream>>>(att_w, mlp_w, w_in, Wt, winp);
  k_count<<<(EE + 255) / 256, 256, 0, stream>>>(srcp, EE, deg);
  k_count<<<(NN + 255) / 256, 256, 0, stream>>>(batch, NN, gcnt);
  k_scan_excl<<<1, 1024, 0, stream>>>(deg, NN, rowp, cursor);
  k_scan_excl<<<1, 1024, 0, stream>>>(gcnt, GG, gptr, nullptr);
  k_scatter<<<(EE + 255) / 256, 256, 0, stream>>>(srcp, dstp, EE, cursor, dsts);

  // input: T0 -> A ; H point -> (Hb, ptH)
  k_gemm2<MF_T | MF_P><<<GEMMG, 256, 0, stream>>>(x, IN_F, IN_F, winp, nullptr, A, Hb, ptH, cptr, NN);

  // ---- layer 0 ----
  k_gemm2<MF_P><<<GEMMG, 256, 0, stream>>>(A, 128, 128, Wt + 0 * 16384, att_b + 0 * DD, nullptr, HLb, ptHL, cptr, NN);
  k_agg_f<<<EW, 256, 0, stream>>>(Hb, ptH, HLb, ptHL, A, rowp, dsts, epsv + 0, cptr, B, NN);
  k_gemm2<MF_TANH | MF_T><<<GEMMG, 256, 0, stream>>>(B, 128, 128, Wt + 2 * 16384, mlp_b + 0 * DD, A, nullptr, nullptr, cptr, NN);
  k_gemm2<MF_TANH | MF_T | MF_P><<<GEMMG, 256, 0, stream>>>(A, 128, 128, Wt + 3 * 16384, mlp_b + 1 * DD, B, Hb, ptH, cptr, NN);
  k_pool<<<GG, 128, 0, stream>>>(B, gptr, out, 0);

  // ---- layer 1 ----
  k_gemm2<MF_P><<<GEMMG, 256, 0, stream>>>(B, 128, 128, Wt + 1 * 16384, att_b + 1 * DD, nullptr, HLb, ptHL, cptr, NN);
  k_agg_f<<<EW, 256, 0, stream>>>(Hb, ptH, HLb, ptHL, B, rowp, dsts, epsv + 1, cptr, A, NN);
  k_gemm2<MF_TANH | MF_T><<<GEMMG, 256, 0, stream>>>(A, 128, 128, Wt + 4 * 16384, mlp_b + 2 * DD, A, nullptr, nullptr, cptr, NN);
  k_gemm2<MF_TANH | MF_T><<<GEMMG, 256, 0, stream>>>(A, 128, 128, Wt + 5 * 16384, mlp_b + 3 * DD, B, nullptr, nullptr, cptr, NN);
  k_pool<<<GG, 128, 0, stream>>>(B, gptr, out, 1);
}

// Round 4
// 695.542 us; speedup vs baseline: 2.1146x; 1.2185x over previous
//
#include <hip/hip_runtime.h>
#include <math.h>

#define NN 50000
#define NNP 50048
#define EE 800000
#define IN_F 200
#define DD 127
#define GG 512
#define EPSH 1e-5f

typedef unsigned int u32;
typedef unsigned short u16;
typedef __attribute__((ext_vector_type(8))) short short8;
typedef __attribute__((ext_vector_type(4))) float f32x4;

__device__ __forceinline__ float wsum(float v) {
#pragma unroll
  for (int off = 32; off > 0; off >>= 1) v += __shfl_xor(v, off);
  return v;
}

__device__ __forceinline__ u32 bf16r(float x) {  // round-to-nearest-even bf16 bits
  u32 u = __float_as_uint(x);
  return (u + 0x7fffu + ((u >> 16) & 1u)) >> 16;
}

__device__ __forceinline__ u32 packhl(float v) {  // u32 = bf16_hi | bf16_lo<<16 (hi+lo ~ fp32)
  u32 hi = bf16r(v);
  float vh = __uint_as_float(hi << 16);
  u32 lo = bf16r(v - vh);
  return hi | (lo << 16);
}

__device__ __forceinline__ float rec(u32 u) {  // reconstruct fp32 from packhl
  return __uint_as_float(u << 16) + __uint_as_float(u & 0xffff0000u);
}

// ---------------- prep: weights -> bf16 hi/lo fragment layout ----------------
// Frag layout per matrix: [q][t][lane][j] bf16; B[k][n], k=q*32+(lane>>4)*8+j, n=t*16+(lane&15)
// Input mat (7 chunks, 28672 elems) at offset 0; layer mats m=0..5 (4 chunks, 16384) at 28672+m*16384.
#define WF_TOT (28672 + 6 * 16384)
__global__ void k_prep_wf(const float* __restrict__ att_w, const float* __restrict__ mlp_w,
                          const float* __restrict__ w_in, u16* __restrict__ Wfh,
                          u16* __restrict__ Wfl) {
  for (int idx = blockIdx.x * 256 + threadIdx.x; idx < WF_TOT; idx += gridDim.x * 256) {
    float val;
    if (idx < 28672) {
      int q = idx >> 12, rem = idx & 4095;
      int t = rem >> 9, l = (rem >> 3) & 63, j = rem & 7;
      int k = q * 32 + ((l >> 4) << 3) + j, n = t * 16 + (l & 15);
      val = (k < IN_F && n < DD) ? w_in[k * DD + n] : 0.f;
    } else {
      int rel = idx - 28672;
      int mat = rel >> 14, rem = rel & 16383;
      int q = rem >> 12;
      rem &= 4095;
      int t = rem >> 9, l = (rem >> 3) & 63, j = rem & 7;
      int k = q * 32 + ((l >> 4) << 3) + j, n = t * 16 + (l & 15);
      const float* wsrc = (mat < 2) ? att_w + mat * DD * DD : mlp_w + (mat - 2) * DD * DD;
      val = (k < DD && n < DD) ? wsrc[n * DD + k] : 0.f;
    }
    u32 hi = bf16r(val);
    float vh = __uint_as_float(hi << 16);
    u32 lo = bf16r(val - vh);
    Wfh[idx] = (u16)hi;
    Wfl[idx] = (u16)lo;
  }
}

// ---------------- CSR build ----------------
__global__ void k_count(const int* __restrict__ idx, int n, int* __restrict__ cnt) {
  int i = blockIdx.x * blockDim.x + threadIdx.x;
  if (i < n) atomicAdd(&cnt[idx[i]], 1);
}

__global__ __launch_bounds__(1024) void k_scan_excl(const int* __restrict__ in, int n,
                                                    int* __restrict__ out, int* __restrict__ cur) {
  __shared__ int wbase[16];
  __shared__ int chunk_tot;
  int tid = threadIdx.x;
  int lane = tid & 63;
  int w = tid >> 6;
  int carry = 0;
  for (int base = 0; base < n; base += 1024) {
    int i = base + tid;
    int x = (i < n) ? in[i] : 0;
    int incl = x;
#pragma unroll
    for (int off = 1; off < 64; off <<= 1) {
      int v = __shfl_up(incl, off);
      if (lane >= off) incl += v;
    }
    if (lane == 63) wbase[w] = incl;
    __syncthreads();
    if (w == 0) {
      int t = (lane < 16) ? wbase[lane] : 0;
      int it = t;
#pragma unroll
      for (int off = 1; off < 16; off <<= 1) {
        int v = __shfl_up(it, off);
        if (lane >= off) it += v;
      }
      if (lane < 16) wbase[lane] = it - t;
      if (lane == 15) chunk_tot = it;
    }
    __syncthreads();
    int excl = carry + wbase[w] + (incl - x);
    if (i < n) {
      out[i] = excl;
      if (cur) cur[i] = excl;
    }
    carry += chunk_tot;
    __syncthreads();
  }
  if (tid == 0) out[n] = carry;
}

__global__ void k_scatter(const int* __restrict__ src, const int* __restrict__ dst, int n,
                          int* __restrict__ cursor, int* __restrict__ dst_sorted) {
  int e = blockIdx.x * blockDim.x + threadIdx.x;
  if (e < n) {
    int s = src[e];
    int slot = atomicAdd(&cursor[s], 1);
    dst_sorted[slot] = dst[e];
  }
}

// ---------------- split-bf16 MFMA GEMM + fused epilogues ----------------
// D[i][j] = sum_k A[i][k]*B[k][j] + bias[j]; wave = 16 rows x 128 cols.
// A source: AF32 ? fp32 (stride 200, 7 chunks, guarded) : packhl-u32 (stride 128, 4 chunks).
// MODE: 1=tanh, 2=store packhl tangent To, 4=store point (Pb bf16 pairs (c,c+64), Pt time)
#define MF_TANH 1
#define MF_T 2
#define MF_P 4

template <int MODE, int AF32>
__global__ __launch_bounds__(256) void k_mgemm(const float* __restrict__ Af,
                                               const u32* __restrict__ A32,
                                               const u16* __restrict__ Wfh,
                                               const u16* __restrict__ Wfl,
                                               const float* __restrict__ bias,
                                               u32* __restrict__ To, u32* __restrict__ Pb,
                                               float* __restrict__ Pt,
                                               const float* __restrict__ cptr, int M) {
  constexpr int NCH = AF32 ? 7 : 4;
  int lane = threadIdx.x & 63, wid = threadIdx.x >> 6;
  int m0 = blockIdx.x * 64 + wid * 16;
  int mld = m0 + (lane & 15);  // A-fragment row for this lane
  int quad = lane >> 4;
  f32x4 acc[8];
#pragma unroll
  for (int t = 0; t < 8; t++) acc[t] = (f32x4){0.f, 0.f, 0.f, 0.f};
#pragma unroll
  for (int q = 0; q < NCH; q++) {
    int k0 = q * 32 + quad * 8;
    union {
      short8 v;
      u32 w[4];
    } ah, al;
    if (AF32) {
      bool ok = (mld < M) && (k0 + 7 < IN_F);
      const float* ap = Af + (size_t)mld * IN_F + k0;
      float4 x0 = ok ? *(const float4*)ap : make_float4(0.f, 0.f, 0.f, 0.f);
      float4 x1 = ok ? *(const float4*)(ap + 4) : make_float4(0.f, 0.f, 0.f, 0.f);
      float xv[8] = {x0.x, x0.y, x0.z, x0.w, x1.x, x1.y, x1.z, x1.w};
#pragma unroll
      for (int p = 0; p < 4; p++) {
        u32 h0 = bf16r(xv[2 * p]), h1 = bf16r(xv[2 * p + 1]);
        float f0 = __uint_as_float(h0 << 16), f1 = __uint_as_float(h1 << 16);
        ah.w[p] = h0 | (h1 << 16);
        al.w[p] = bf16r(xv[2 * p] - f0) | (bf16r(xv[2 * p + 1] - f1) << 16);
      }
    } else {
      const u32* ap = A32 + (size_t)mld * 128 + k0;
      uint4 u0 = *(const uint4*)ap;
      uint4 u1 = *(const uint4*)(ap + 4);
      u32 uu[8] = {u0.x, u0.y, u0.z, u0.w, u1.x, u1.y, u1.z, u1.w};
#pragma unroll
      for (int p = 0; p < 4; p++) {
        ah.w[p] = __builtin_amdgcn_perm(uu[2 * p + 1], uu[2 * p], 0x05040100u);
        al.w[p] = __builtin_amdgcn_perm(uu[2 * p + 1], uu[2 * p], 0x07060302u);
      }
    }
    const u16* bph = Wfh + ((size_t)(q * 8) * 64 + lane) * 8;
    const u16* bpl = Wfl + ((size_t)(q * 8) * 64 + lane) * 8;
#pragma unroll
    for (int t = 0; t < 8; t++) {
      short8 bh = *(const short8*)(bph + t * 512);
      short8 bl = *(const short8*)(bpl + t * 512);
      acc[t] = __builtin_amdgcn_mfma_f32_16x16x32_bf16(ah.v, bh, acc[t], 0, 0, 0);
      acc[t] = __builtin_amdgcn_mfma_f32_16x16x32_bf16(al.v, bh, acc[t], 0, 0, 0);
      acc[t] = __builtin_amdgcn_mfma_f32_16x16x32_bf16(ah.v, bl, acc[t], 0, 0, 0);
    }
  }
  // ---- epilogue: D layout col = t*16+(lane&15), row = m0 + quad*4 + r ----
  int m = lane & 15;
  float bj[8];
#pragma unroll
  for (int t = 0; t < 8; t++) {
    int col = t * 16 + m;
    bj[t] = (bias != nullptr && col < DD) ? bias[col] : 0.f;
  }
  float cc = 1.f, sc = 1.f;
  if (MODE & MF_P) {
    cc = *cptr;
    sc = sqrtf(cc);
  }
#pragma unroll
  for (int r = 0; r < 4; r++) {
    int rowD = m0 + quad * 4 + r;
    float vs[8];
#pragma unroll
    for (int t = 0; t < 8; t++) {
      float v = acc[t][r] + bj[t];
      if (MODE & MF_TANH) {
        float e = exp2f(v * 2.8853900817779268f);  // exp(2v)
        v = 1.f - 2.f / (e + 1.f);
      }
      vs[t] = v;
    }
    if ((MODE & MF_T) && rowD < M) {
      u32* to = To + (size_t)rowD * 128 + m;
#pragma unroll
      for (int t = 0; t < 8; t++) to[t * 16] = packhl(vs[t]);
    }
    if (MODE & MF_P) {
      float ps = 0.f;
#pragma unroll
      for (int t = 0; t < 8; t++) ps += vs[t] * vs[t];
#pragma unroll
      for (int off = 1; off < 16; off <<= 1) ps += __shfl_xor(ps, off);
      float nn = fmaxf(sqrtf(ps), 1e-9f);
      float e = expf(nn / sc);
      float f = sc * (e - 1.f / e) * 0.5f / nn;  // sc*sinh(nn/sc)/nn
      float tt = sqrtf(cc + f * f * ps);
      if (rowD < M) {
        u32* pb = Pb + (size_t)rowD * 64 + m;
#pragma unroll
        for (int t = 0; t < 4; t++)
          pb[t * 16] = bf16r(f * vs[t]) | (bf16r(f * vs[t + 4]) << 16);
        if (m == 0) Pt[rowD] = tt;
      }
    }
  }
}

// ---------------- fused attention + aggregation + GIN combine ----------------
// Point rows bf16: u32 i of a row = cols {i (lo), i+64 (hi)}. Tangent rows: packhl u32 per col.
__global__ void k_agg_f(const u32* __restrict__ Hb, const float* __restrict__ ptH,
                        const u32* __restrict__ HLb, const float* __restrict__ ptHL,
                        const u32* __restrict__ T, const int* __restrict__ rowp,
                        const int* __restrict__ dsts, const float* __restrict__ epsp,
                        const float* __restrict__ cptr, u32* __restrict__ Tout, int n) {
  int node = blockIdx.x * 4 + (threadIdx.x >> 6);
  int lane = threadIdx.x & 63;
  if (node >= n) return;
  float c = *cptr, sc = sqrtf(c), rcpc = 1.f / c;
  float eps = *epsp;
  u32 au = HLb[(size_t)node * 64 + lane];
  float a0 = __uint_as_float(au << 16);
  float a1 = __uint_as_float(au & 0xffff0000u);
  float pts = ptHL[node];
  int e0 = rowp[node], e1 = rowp[node + 1];
  float m0 = 0.f, m1 = 0.f, mt = 0.f;
  for (int e = e0; e < e1; e++) {
    int d = dsts[e];
    u32 bu = HLb[(size_t)d * 64 + lane];
    u32 hu = Hb[(size_t)d * 64 + lane];
    float ptd = ptHL[d];
    float pth = ptH[d];
    float b0 = __uint_as_float(bu << 16);
    float b1 = __uint_as_float(bu & 0xffff0000u);
    float sp = wsum(a0 * b0 + a1 * b1);
    float val = fmaxf((pts * ptd - sp) * rcpc, 1.f + EPSH);
    float w = val + sqrtf(val * val - 1.f);
    float att = exp2f(-sc * __log2f(w));  // exp(-sc*acosh(val))
    float h0 = __uint_as_float(hu << 16);
    float h1 = __uint_as_float(hu & 0xffff0000u);
    m0 = fmaf(att, h0, m0);
    m1 = fmaf(att, h1, m1);
    mt = fmaf(att, pth, mt);
  }
  float lsq = wsum(m0 * m0 + m1 * m1);
  float neg_inner = mt * mt - lsq;  // -l_inner(m,m)
  float denom = sqrtf(fmaxf(neg_inner, 1e-9f));
  float r = sc / denom;
  float ssq = r * r * lsq;
  float agg0 = sqrtf(c + ssq);
  float ynA = fmaxf(sqrtf(ssq), 1e-9f);
  float v2 = fmaxf(agg0 / sc, 1.f + EPSH);
  float dA = sc * 0.69314718056f * __log2f(v2 + sqrtf(v2 * v2 - 1.f));  // sc*acosh
  float sca = dA * r / ynA;
  float tx = rec(T[(size_t)node * 128 + lane]);
  float ty = rec(T[(size_t)node * 128 + lane + 64]);
  float v0 = sca * m0 + (1.f + eps) * tx;
  float v1 = sca * m1 + (1.f + eps) * ty;
  Tout[(size_t)node * 128 + lane] = packhl(v0);
  Tout[(size_t)node * 128 + lane + 64] = packhl(v1);
}

// ---------------- pooling ----------------
__global__ void k_pool(const u32* __restrict__ U, const int* __restrict__ gptr,
                       float* __restrict__ out, int layer) {
  int g = blockIdx.x;
  int c = threadIdx.x;  // 0..127
  int s = gptr[g], e = gptr[g + 1];
  float acc = 0.f;
  if (c > 0) {
    const u32* up = U + (c - 1);
    int i = s;
    float a0 = 0.f, a1 = 0.f, a2 = 0.f, a3 = 0.f;
    for (; i + 3 < e; i += 4) {
      a0 += rec(up[(size_t)i * 128]);
      a1 += rec(up[(size_t)(i + 1) * 128]);
      a2 += rec(up[(size_t)(i + 2) * 128]);
      a3 += rec(up[(size_t)(i + 3) * 128]);
    }
    for (; i < e; i++) a0 += rec(up[(size_t)i * 128]);
    acc = (a0 + a1) + (a2 + a3);
  }
  out[(size_t)g * 256 + layer * 128 + c] = acc;
}

// ---------------- launch ----------------
extern "C" void kernel_launch(void* const* d_in, const int* in_sizes, int n_in, void* d_out,
                              int out_size, void* d_ws, size_t ws_size, hipStream_t stream) {
  const float* x = (const float*)d_in[0];
  const float* cptr = (const float*)d_in[1];
  const float* w_in = (const float*)d_in[2];
  const float* att_w = (const float*)d_in[3];
  const float* att_b = (const float*)d_in[4];
  const float* epsv = (const float*)d_in[5];
  const float* mlp_w = (const float*)d_in[6];
  const float* mlp_b = (const float*)d_in[7];
  const int* ei = (const int*)d_in[8];
  const int* batch = (const int*)d_in[9];
  const int* srcp = ei;
  const int* dstp = ei + EE;
  float* out = (float*)d_out;

  u32* ws = (u32*)d_ws;
  u16* Wfh = (u16*)ws;                // WF_TOT u16 = 63488 u32
  u16* Wfl = Wfh + WF_TOT;            // 63488 u32
  size_t off = (WF_TOT * 2 + 3) / 4 * 2;  // u32 offset after both (WF_TOT even): 126976
  int* deg = (int*)(ws + 126976);     // N
  int* gcnt = deg + NN;               // G (contiguous with deg: one memset)
  int* rowp = gcnt + GG;              // N+1
  int* cursor = rowp + NN + 1;        // N
  int* gptr = cursor + NN;            // G+1
  int* dsts = gptr + GG + 1;          // E
  float* ptH = (float*)(dsts + EE);   // NNP
  float* ptHL = ptH + NNP;            // NNP
  size_t o2 = (size_t)((u32*)(ptHL + NNP) - ws);
  o2 = (o2 + 3) & ~(size_t)3;  // 16B align
  u32* Hb = ws + o2;                  // NNP*64
  u32* HLb = Hb + (size_t)NNP * 64;   // NNP*64
  u32* A32 = HLb + (size_t)NNP * 64;  // NNP*128
  u32* B32 = A32 + (size_t)NNP * 128; // NNP*128

  const int EW = 12500;                // agg: 4 nodes/block
  const int GEMMG = (NN + 63) / 64;    // 782 blocks, wave=16 rows

  hipMemsetAsync(deg, 0, (NN + GG) * sizeof(int), stream);
  k_prep_wf<<<64, 256, 0, stream>>>(att_w, mlp_w, w_in, Wfh, Wfl);
  k_count<<<(EE + 255) / 256, 256, 0, stream>>>(srcp, EE, deg);
  k_count<<<(NN + 255) / 256, 256, 0, stream>>>(batch, NN, gcnt);
  k_scan_excl<<<1, 1024, 0, stream>>>(deg, NN, rowp, cursor);
  k_scan_excl<<<1, 1024, 0, stream>>>(gcnt, GG, gptr, nullptr);
  k_scatter<<<(EE + 255) / 256, 256, 0, stream>>>(srcp, dstp, EE, cursor, dsts);

  const u16* wIh = Wfh;              // input mat frags (7 chunks)
  const u16* wIl = Wfl;
#define WH(m) (Wfh + 28672 + (m) * 16384)
#define WL(m) (Wfl + 28672 + (m) * 16384)

  // input: T0 -> A32 ; H point -> (Hb, ptH)
  k_mgemm<MF_T | MF_P, 1><<<GEMMG, 256, 0, stream>>>(x, nullptr, wIh, wIl, nullptr, A32, Hb, ptH, cptr, NN);

  // ---- layer 0 ----
  k_mgemm<MF_P, 0><<<GEMMG, 256, 0, stream>>>(nullptr, A32, WH(0), WL(0), att_b, nullptr, HLb, ptHL, cptr, NN);
  k_agg_f<<<EW, 256, 0, stream>>>(Hb, ptH, HLb, ptHL, A32, rowp, dsts, epsv + 0, cptr, B32, NN);
  k_mgemm<MF_TANH | MF_T, 0><<<GEMMG, 256, 0, stream>>>(nullptr, B32, WH(2), WL(2), mlp_b + 0 * DD, B32, nullptr, nullptr, cptr, NN);
  k_mgemm<MF_TANH | MF_T | MF_P, 0><<<GEMMG, 256, 0, stream>>>(nullptr, B32, WH(3), WL(3), mlp_b + 1 * DD, A32, Hb, ptH, cptr, NN);
  k_pool<<<GG, 128, 0, stream>>>(A32, gptr, out, 0);

  // ---- layer 1 ----
  k_mgemm<MF_P, 0><<<GEMMG, 256, 0, stream>>>(nullptr, A32, WH(1), WL(1), att_b + DD, nullptr, HLb, ptHL, cptr, NN);
  k_agg_f<<<EW, 256, 0, stream>>>(Hb, ptH, HLb, ptHL, A32, rowp, dsts, epsv + 1, cptr, B32, NN);
  k_mgemm<MF_TANH | MF_T, 0><<<GEMMG, 256, 0, stream>>>(nullptr, B32, WH(4), WL(4), mlp_b + 2 * DD, B32, nullptr, nullptr, cptr, NN);
  k_mgemm<MF_TANH | MF_T, 0><<<GEMMG, 256, 0, stream>>>(nullptr, B32, WH(5), WL(5), mlp_b + 3 * DD, B32, nullptr, nullptr, cptr, NN);
  k_pool<<<GG, 128, 0, stream>>>(B32, gptr, out, 1);
}

// Round 5
// 587.590 us; speedup vs baseline: 2.5031x; 1.1837x over previous
//
#include <hip/hip_runtime.h>
#include <math.h>

#define NN 50000
#define NNP 50048
#define EE 800000
#define IN_F 200
#define DD 127
#define GG 512
#define EPSH 1e-5f

typedef unsigned int u32;
typedef unsigned short u16;
typedef __attribute__((ext_vector_type(8))) short short8;
typedef __attribute__((ext_vector_type(4))) float f32x4;

__device__ __forceinline__ u32 bf16r(float x) {  // round-to-nearest-even bf16 bits
  u32 u = __float_as_uint(x);
  return (u + 0x7fffu + ((u >> 16) & 1u)) >> 16;
}

__device__ __forceinline__ u32 packhl(float v) {  // u32 = bf16_hi | bf16_lo<<16 (hi+lo ~ fp32)
  u32 hi = bf16r(v);
  float vh = __uint_as_float(hi << 16);
  u32 lo = bf16r(v - vh);
  return hi | (lo << 16);
}

__device__ __forceinline__ float rec(u32 u) {  // reconstruct fp32 from packhl
  return __uint_as_float(u << 16) + __uint_as_float(u & 0xffff0000u);
}

// ---------------- prep: weights -> bf16 hi/lo fragment layout ----------------
#define WF_TOT (28672 + 6 * 16384)
__global__ void k_prep_wf(const float* __restrict__ att_w, const float* __restrict__ mlp_w,
                          const float* __restrict__ w_in, u16* __restrict__ Wfh,
                          u16* __restrict__ Wfl) {
  for (int idx = blockIdx.x * 256 + threadIdx.x; idx < WF_TOT; idx += gridDim.x * 256) {
    float val;
    if (idx < 28672) {
      int q = idx >> 12, rem = idx & 4095;
      int t = rem >> 9, l = (rem >> 3) & 63, j = rem & 7;
      int k = q * 32 + ((l >> 4) << 3) + j, n = t * 16 + (l & 15);
      val = (k < IN_F && n < DD) ? w_in[k * DD + n] : 0.f;
    } else {
      int rel = idx - 28672;
      int mat = rel >> 14, rem = rel & 16383;
      int q = rem >> 12;
      rem &= 4095;
      int t = rem >> 9, l = (rem >> 3) & 63, j = rem & 7;
      int k = q * 32 + ((l >> 4) << 3) + j, n = t * 16 + (l & 15);
      const float* wsrc = (mat < 2) ? att_w + mat * DD * DD : mlp_w + (mat - 2) * DD * DD;
      val = (k < DD && n < DD) ? wsrc[n * DD + k] : 0.f;
    }
    u32 hi = bf16r(val);
    float vh = __uint_as_float(hi << 16);
    u32 lo = bf16r(val - vh);
    Wfh[idx] = (u16)hi;
    Wfl[idx] = (u16)lo;
  }
}

// ---------------- CSR build ----------------
__global__ void k_count(const int* __restrict__ idx, int n, int* __restrict__ cnt) {
  int i = blockIdx.x * blockDim.x + threadIdx.x;
  if (i < n) atomicAdd(&cnt[idx[i]], 1);
}

__global__ __launch_bounds__(1024) void k_scan_excl(const int* __restrict__ in, int n,
                                                    int* __restrict__ out, int* __restrict__ cur) {
  __shared__ int wbase[16];
  __shared__ int chunk_tot;
  int tid = threadIdx.x;
  int lane = tid & 63;
  int w = tid >> 6;
  int carry = 0;
  for (int base = 0; base < n; base += 1024) {
    int i = base + tid;
    int x = (i < n) ? in[i] : 0;
    int incl = x;
#pragma unroll
    for (int off = 1; off < 64; off <<= 1) {
      int v = __shfl_up(incl, off);
      if (lane >= off) incl += v;
    }
    if (lane == 63) wbase[w] = incl;
    __syncthreads();
    if (w == 0) {
      int t = (lane < 16) ? wbase[lane] : 0;
      int it = t;
#pragma unroll
      for (int off = 1; off < 16; off <<= 1) {
        int v = __shfl_up(it, off);
        if (lane >= off) it += v;
      }
      if (lane < 16) wbase[lane] = it - t;
      if (lane == 15) chunk_tot = it;
    }
    __syncthreads();
    int excl = carry + wbase[w] + (incl - x);
    if (i < n) {
      out[i] = excl;
      if (cur) cur[i] = excl;
    }
    carry += chunk_tot;
    __syncthreads();
  }
  if (tid == 0) out[n] = carry;
}

__global__ void k_scatter(const int* __restrict__ src, const int* __restrict__ dst, int n,
                          int* __restrict__ cursor, int* __restrict__ dst_sorted) {
  int e = blockIdx.x * blockDim.x + threadIdx.x;
  if (e < n) {
    int s = src[e];
    int slot = atomicAdd(&cursor[s], 1);
    dst_sorted[slot] = dst[e];
  }
}

// gptr[g] = lower_bound(batch, g) on the sorted batch array
__global__ void k_gptr(const int* __restrict__ batch, int* __restrict__ gptr) {
  int g = blockIdx.x * blockDim.x + threadIdx.x;
  if (g > GG) return;
  int lo = 0, hi = NN;
  while (lo < hi) {
    int mid = (lo + hi) >> 1;
    if (batch[mid] < g) lo = mid + 1; else hi = mid;
  }
  gptr[g] = lo;
}

// ---------------- split-bf16 MFMA GEMM + fused epilogues ----------------
#define MF_TANH 1
#define MF_T 2
#define MF_P 4

template <int MODE, int AF32>
__global__ __launch_bounds__(256) void k_mgemm(const float* __restrict__ Af,
                                               const u32* __restrict__ A32,
                                               const u16* __restrict__ Wfh,
                                               const u16* __restrict__ Wfl,
                                               const float* __restrict__ bias,
                                               u32* __restrict__ To, u32* __restrict__ Pb,
                                               float* __restrict__ Pt,
                                               const float* __restrict__ cptr, int M) {
  constexpr int NCH = AF32 ? 7 : 4;
  int lane = threadIdx.x & 63, wid = threadIdx.x >> 6;
  int m0 = blockIdx.x * 64 + wid * 16;
  int mld = m0 + (lane & 15);
  int quad = lane >> 4;
  f32x4 acc[8];
#pragma unroll
  for (int t = 0; t < 8; t++) acc[t] = (f32x4){0.f, 0.f, 0.f, 0.f};
#pragma unroll
  for (int q = 0; q < NCH; q++) {
    int k0 = q * 32 + quad * 8;
    union {
      short8 v;
      u32 w[4];
    } ah, al;
    if (AF32) {
      bool ok = (mld < M) && (k0 + 7 < IN_F);
      const float* ap = Af + (size_t)mld * IN_F + k0;
      float4 x0 = ok ? *(const float4*)ap : make_float4(0.f, 0.f, 0.f, 0.f);
      float4 x1 = ok ? *(const float4*)(ap + 4) : make_float4(0.f, 0.f, 0.f, 0.f);
      float xv[8] = {x0.x, x0.y, x0.z, x0.w, x1.x, x1.y, x1.z, x1.w};
#pragma unroll
      for (int p = 0; p < 4; p++) {
        u32 h0 = bf16r(xv[2 * p]), h1 = bf16r(xv[2 * p + 1]);
        float f0 = __uint_as_float(h0 << 16), f1 = __uint_as_float(h1 << 16);
        ah.w[p] = h0 | (h1 << 16);
        al.w[p] = bf16r(xv[2 * p] - f0) | (bf16r(xv[2 * p + 1] - f1) << 16);
      }
    } else {
      const u32* ap = A32 + (size_t)mld * 128 + k0;
      uint4 u0 = *(const uint4*)ap;
      uint4 u1 = *(const uint4*)(ap + 4);
      u32 uu[8] = {u0.x, u0.y, u0.z, u0.w, u1.x, u1.y, u1.z, u1.w};
#pragma unroll
      for (int p = 0; p < 4; p++) {
        ah.w[p] = __builtin_amdgcn_perm(uu[2 * p + 1], uu[2 * p], 0x05040100u);
        al.w[p] = __builtin_amdgcn_perm(uu[2 * p + 1], uu[2 * p], 0x07060302u);
      }
    }
    const u16* bph = Wfh + ((size_t)(q * 8) * 64 + lane) * 8;
    const u16* bpl = Wfl + ((size_t)(q * 8) * 64 + lane) * 8;
#pragma unroll
    for (int t = 0; t < 8; t++) {
      short8 bh = *(const short8*)(bph + t * 512);
      short8 bl = *(const short8*)(bpl + t * 512);
      acc[t] = __builtin_amdgcn_mfma_f32_16x16x32_bf16(ah.v, bh, acc[t], 0, 0, 0);
      acc[t] = __builtin_amdgcn_mfma_f32_16x16x32_bf16(al.v, bh, acc[t], 0, 0, 0);
      acc[t] = __builtin_amdgcn_mfma_f32_16x16x32_bf16(ah.v, bl, acc[t], 0, 0, 0);
    }
  }
  int m = lane & 15;
  float bj[8];
#pragma unroll
  for (int t = 0; t < 8; t++) {
    int col = t * 16 + m;
    bj[t] = (bias != nullptr && col < DD) ? bias[col] : 0.f;
  }
  float cc = 1.f, sc = 1.f;
  if (MODE & MF_P) {
    cc = *cptr;
    sc = sqrtf(cc);
  }
#pragma unroll
  for (int r = 0; r < 4; r++) {
    int rowD = m0 + quad * 4 + r;
    float vs[8];
#pragma unroll
    for (int t = 0; t < 8; t++) {
      float v = acc[t][r] + bj[t];
      if (MODE & MF_TANH) {
        float e = exp2f(v * 2.8853900817779268f);  // exp(2v)
        v = 1.f - 2.f / (e + 1.f);
      }
      vs[t] = v;
    }
    if ((MODE & MF_T) && rowD < M) {
      u32* to = To + (size_t)rowD * 128 + m;
#pragma unroll
      for (int t = 0; t < 8; t++) to[t * 16] = packhl(vs[t]);
    }
    if (MODE & MF_P) {
      float ps = 0.f;
#pragma unroll
      for (int t = 0; t < 8; t++) ps += vs[t] * vs[t];
#pragma unroll
      for (int off = 1; off < 16; off <<= 1) ps += __shfl_xor(ps, off);
      float nn = fmaxf(sqrtf(ps), 1e-9f);
      float e = expf(nn / sc);
      float f = sc * (e - 1.f / e) * 0.5f / nn;  // sc*sinh(nn/sc)/nn
      float tt = sqrtf(cc + f * f * ps);
      if (rowD < M) {
        u32* pb = Pb + (size_t)rowD * 64 + m;
#pragma unroll
        for (int t = 0; t < 4; t++)
          pb[t * 16] = bf16r(f * vs[t]) | (bf16r(f * vs[t + 4]) << 16);
        if (m == 0) Pt[rowD] = tt;
      }
    }
  }
}

// ---------------- fused attention + aggregation, quarter-wave ----------------
// Each 16-lane quarter owns one edge; lane p of a quarter covers u32 slots 4p..4p+3
// of the 64-u32 bf16 point row (= cols 4p..4p+3 lo, 64+4p..64+4p+3 hi).
__global__ void k_agg_q(const u32* __restrict__ Hb, const float* __restrict__ ptH,
                        const u32* __restrict__ HLb, const float* __restrict__ ptHL,
                        const u32* __restrict__ T, const int* __restrict__ rowp,
                        const int* __restrict__ dsts, const float* __restrict__ epsp,
                        const float* __restrict__ cptr, u32* __restrict__ Tout, int n) {
  int node = blockIdx.x * 4 + (threadIdx.x >> 6);
  int lane = threadIdx.x & 63;
  if (node >= n) return;
  int p = lane & 15;
  int q = lane >> 4;
  float c = *cptr, sc = sqrtf(c), rcpc = 1.f / c;
  float eps = *epsp;
  // own HL slice (uint4 = 8 bf16 elems)
  uint4 a4 = *(const uint4*)(HLb + (size_t)node * 64 + p * 4);
  float alo[4], ahi[4];
  {
    u32 aw[4] = {a4.x, a4.y, a4.z, a4.w};
#pragma unroll
    for (int j = 0; j < 4; j++) {
      alo[j] = __uint_as_float(aw[j] << 16);
      ahi[j] = __uint_as_float(aw[j] & 0xffff0000u);
    }
  }
  float pts = ptHL[node];
  int e0 = rowp[node], e1 = rowp[node + 1];
  int iters = (e1 - e0 + 3) >> 2;
  float m[8] = {0.f, 0.f, 0.f, 0.f, 0.f, 0.f, 0.f, 0.f};
  float mt = 0.f;
#pragma unroll 2
  for (int it = 0; it < iters; it++) {
    int e = e0 + it * 4 + q;
    bool ve = e < e1;
    int ei = ve ? e : e0;
    int d = dsts[ei];
    uint4 b4 = *(const uint4*)(HLb + (size_t)d * 64 + p * 4);
    float ptd = ptHL[d];
    float pth = ptH[d];
    u32 bw[4] = {b4.x, b4.y, b4.z, b4.w};
    float dot = 0.f;
#pragma unroll
    for (int j = 0; j < 4; j++) {
      dot = fmaf(alo[j], __uint_as_float(bw[j] << 16), dot);
      dot = fmaf(ahi[j], __uint_as_float(bw[j] & 0xffff0000u), dot);
    }
#pragma unroll
    for (int off = 1; off < 16; off <<= 1) dot += __shfl_xor(dot, off);
    float valv = fmaxf((pts * ptd - dot) * rcpc, 1.f + EPSH);
    float w = valv + sqrtf(fmaf(valv, valv, -1.f));
    float att = exp2f(-sc * __log2f(w));
    att = ve ? att : 0.f;
    uint4 h4 = *(const uint4*)(Hb + (size_t)d * 64 + p * 4);
    u32 hw[4] = {h4.x, h4.y, h4.z, h4.w};
#pragma unroll
    for (int j = 0; j < 4; j++) {
      m[j] = fmaf(att, __uint_as_float(hw[j] << 16), m[j]);
      m[4 + j] = fmaf(att, __uint_as_float(hw[j] & 0xffff0000u), m[4 + j]);
    }
    mt = fmaf(att, pth, mt);
  }
  // combine quarters
#pragma unroll
  for (int j = 0; j < 8; j++) {
    m[j] += __shfl_xor(m[j], 16);
    m[j] += __shfl_xor(m[j], 32);
  }
  mt += __shfl_xor(mt, 16);
  mt += __shfl_xor(mt, 32);
  float lp = 0.f;
#pragma unroll
  for (int j = 0; j < 8; j++) lp = fmaf(m[j], m[j], lp);
#pragma unroll
  for (int off = 1; off < 16; off <<= 1) lp += __shfl_xor(lp, off);
  float lsq = lp;
  float neg_inner = mt * mt - lsq;
  float denom = sqrtf(fmaxf(neg_inner, 1e-9f));
  float r = sc / denom;
  float ssq = r * r * lsq;
  float agg0 = sqrtf(c + ssq);
  float ynA = fmaxf(sqrtf(ssq), 1e-9f);
  float v2 = fmaxf(agg0 / sc, 1.f + EPSH);
  float dA = sc * 0.69314718056f * __log2f(v2 + sqrtf(v2 * v2 - 1.f));
  float sca = dA * r / ynA;
  // T combine + store (quarter 0 only)
  uint4 t0 = *(const uint4*)(T + (size_t)node * 128 + p * 4);
  uint4 t1 = *(const uint4*)(T + (size_t)node * 128 + 64 + p * 4);
  u32 tw0[4] = {t0.x, t0.y, t0.z, t0.w};
  u32 tw1[4] = {t1.x, t1.y, t1.z, t1.w};
  float oe = 1.f + eps;
  uint4 o0, o1;
  u32* po0 = (u32*)&o0;
  u32* po1 = (u32*)&o1;
#pragma unroll
  for (int j = 0; j < 4; j++) {
    po0[j] = packhl(fmaf(sca, m[j], oe * rec(tw0[j])));
    po1[j] = packhl(fmaf(sca, m[4 + j], oe * rec(tw1[j])));
  }
  if (q == 0) {
    *(uint4*)(Tout + (size_t)node * 128 + p * 4) = o0;
    *(uint4*)(Tout + (size_t)node * 128 + 64 + p * 4) = o1;
  }
}

// ---------------- pooling ----------------
__global__ void k_pool(const u32* __restrict__ U, const int* __restrict__ gptr,
                       float* __restrict__ out, int layer) {
  int g = blockIdx.x;
  int c = threadIdx.x;  // 0..127
  int s = gptr[g], e = gptr[g + 1];
  float acc = 0.f;
  if (c > 0) {
    const u32* up = U + (c - 1);
    int i = s;
    float a0 = 0.f, a1 = 0.f, a2 = 0.f, a3 = 0.f;
    for (; i + 3 < e; i += 4) {
      a0 += rec(up[(size_t)i * 128]);
      a1 += rec(up[(size_t)(i + 1) * 128]);
      a2 += rec(up[(size_t)(i + 2) * 128]);
      a3 += rec(up[(size_t)(i + 3) * 128]);
    }
    for (; i < e; i++) a0 += rec(up[(size_t)i * 128]);
    acc = (a0 + a1) + (a2 + a3);
  }
  out[(size_t)g * 256 + layer * 128 + c] = acc;
}

// ---------------- launch ----------------
extern "C" void kernel_launch(void* const* d_in, const int* in_sizes, int n_in, void* d_out,
                              int out_size, void* d_ws, size_t ws_size, hipStream_t stream) {
  const float* x = (const float*)d_in[0];
  const float* cptr = (const float*)d_in[1];
  const float* w_in = (const float*)d_in[2];
  const float* att_w = (const float*)d_in[3];
  const float* att_b = (const float*)d_in[4];
  const float* epsv = (const float*)d_in[5];
  const float* mlp_w = (const float*)d_in[6];
  const float* mlp_b = (const float*)d_in[7];
  const int* ei = (const int*)d_in[8];
  const int* batch = (const int*)d_in[9];
  const int* srcp = ei;
  const int* dstp = ei + EE;
  float* out = (float*)d_out;

  u32* ws = (u32*)d_ws;
  u16* Wfh = (u16*)ws;                // WF_TOT u16
  u16* Wfl = Wfh + WF_TOT;
  int* deg = (int*)(ws + 126976);     // N
  int* rowp = deg + NN;               // N+1
  int* cursor = rowp + NN + 1;        // N
  int* gptr = cursor + NN;            // G+1
  int* dsts = gptr + GG + 1;          // E
  float* ptH = (float*)(dsts + EE);   // NNP
  float* ptHL = ptH + NNP;            // NNP
  size_t o2 = (size_t)((u32*)(ptHL + NNP) - ws);
  o2 = (o2 + 3) & ~(size_t)3;  // 16B align
  u32* Hb = ws + o2;                  // NNP*64
  u32* HLb = Hb + (size_t)NNP * 64;   // NNP*64
  u32* A32 = HLb + (size_t)NNP * 64;  // NNP*128
  u32* B32 = A32 + (size_t)NNP * 128; // NNP*128

  const int EW = 12500;                // agg: 4 nodes/block
  const int GEMMG = (NN + 63) / 64;

  hipMemsetAsync(deg, 0, NN * sizeof(int), stream);
  k_prep_wf<<<64, 256, 0, stream>>>(att_w, mlp_w, w_in, Wfh, Wfl);
  k_count<<<(EE + 255) / 256, 256, 0, stream>>>(srcp, EE, deg);
  k_gptr<<<3, 256, 0, stream>>>(batch, gptr);
  k_scan_excl<<<1, 1024, 0, stream>>>(deg, NN, rowp, cursor);
  k_scatter<<<(EE + 255) / 256, 256, 0, stream>>>(srcp, dstp, EE, cursor, dsts);

#define WH(m) (Wfh + 28672 + (m) * 16384)
#define WL(m) (Wfl + 28672 + (m) * 16384)

  // input: T0 -> A32 ; H point -> (Hb, ptH)
  k_mgemm<MF_T | MF_P, 1><<<GEMMG, 256, 0, stream>>>(x, nullptr, Wfh, Wfl, nullptr, A32, Hb, ptH, cptr, NN);

  // ---- layer 0 ----
  k_mgemm<MF_P, 0><<<GEMMG, 256, 0, stream>>>(nullptr, A32, WH(0), WL(0), att_b, nullptr, HLb, ptHL, cptr, NN);
  k_agg_q<<<EW, 256, 0, stream>>>(Hb, ptH, HLb, ptHL, A32, rowp, dsts, epsv + 0, cptr, B32, NN);
  k_mgemm<MF_TANH | MF_T, 0><<<GEMMG, 256, 0, stream>>>(nullptr, B32, WH(2), WL(2), mlp_b + 0 * DD, B32, nullptr, nullptr, cptr, NN);
  k_mgemm<MF_TANH | MF_T | MF_P, 0><<<GEMMG, 256, 0, stream>>>(nullptr, B32, WH(3), WL(3), mlp_b + 1 * DD, A32, Hb, ptH, cptr, NN);
  k_pool<<<GG, 128, 0, stream>>>(A32, gptr, out, 0);

  // ---- layer 1 ----
  k_mgemm<MF_P, 0><<<GEMMG, 256, 0, stream>>>(nullptr, A32, WH(1), WL(1), att_b + DD, nullptr, HLb, ptHL, cptr, NN);
  k_agg_q<<<EW, 256, 0, stream>>>(Hb, ptH, HLb, ptHL, A32, rowp, dsts, epsv + 1, cptr, B32, NN);
  k_mgemm<MF_TANH | MF_T, 0><<<GEMMG, 256, 0, stream>>>(nullptr, B32, WH(4), WL(4), mlp_b + 2 * DD, B32, nullptr, nullptr, cptr, NN);
  k_mgemm<MF_TANH | MF_T, 0><<<GEMMG, 256, 0, stream>>>(nullptr, B32, WH(5), WL(5), mlp_b + 3 * DD, B32, nullptr, nullptr, cptr, NN);
  k_pool<<<GG, 128, 0, stream>>>(B32, gptr, out, 1);
}

// Round 6
// 547.025 us; speedup vs baseline: 2.6887x; 1.0742x over previous
//
#include <hip/hip_runtime.h>
#include <math.h>

#define NN 50000
#define NNP 50048
#define EE 800000
#define IN_F 200
#define DD 127
#define GG 512
#define EPSH 1e-5f

typedef unsigned int u32;
typedef unsigned short u16;
typedef __attribute__((ext_vector_type(8))) short short8;
typedef __attribute__((ext_vector_type(4))) float f32x4;

__device__ __forceinline__ u32 bf16r(float x) {  // round-to-nearest-even bf16 bits
  u32 u = __float_as_uint(x);
  return (u + 0x7fffu + ((u >> 16) & 1u)) >> 16;
}

__device__ __forceinline__ u32 packhl(float v) {  // u32 = bf16_hi | bf16_lo<<16
  u32 hi = bf16r(v);
  float vh = __uint_as_float(hi << 16);
  u32 lo = bf16r(v - vh);
  return hi | (lo << 16);
}

__device__ __forceinline__ float rec(u32 u) {  // reconstruct fp32 from packhl
  return __uint_as_float(u << 16) + __uint_as_float(u & 0xffff0000u);
}

// ---------------- prep: weights -> bf16 hi/lo fragment layout ----------------
#define WF_TOT (28672 + 6 * 16384)
__global__ void k_prep_wf(const float* __restrict__ att_w, const float* __restrict__ mlp_w,
                          const float* __restrict__ w_in, u16* __restrict__ Wfh,
                          u16* __restrict__ Wfl) {
  for (int idx = blockIdx.x * 256 + threadIdx.x; idx < WF_TOT; idx += gridDim.x * 256) {
    float val;
    if (idx < 28672) {
      int q = idx >> 12, rem = idx & 4095;
      int t = rem >> 9, l = (rem >> 3) & 63, j = rem & 7;
      int k = q * 32 + ((l >> 4) << 3) + j, n = t * 16 + (l & 15);
      val = (k < IN_F && n < DD) ? w_in[k * DD + n] : 0.f;
    } else {
      int rel = idx - 28672;
      int mat = rel >> 14, rem = rel & 16383;
      int q = rem >> 12;
      rem &= 4095;
      int t = rem >> 9, l = (rem >> 3) & 63, j = rem & 7;
      int k = q * 32 + ((l >> 4) << 3) + j, n = t * 16 + (l & 15);
      const float* wsrc = (mat < 2) ? att_w + mat * DD * DD : mlp_w + (mat - 2) * DD * DD;
      val = (k < DD && n < DD) ? wsrc[n * DD + k] : 0.f;
    }
    u32 hi = bf16r(val);
    float vh = __uint_as_float(hi << 16);
    u32 lo = bf16r(val - vh);
    Wfh[idx] = (u16)hi;
    Wfl[idx] = (u16)lo;
  }
}

// ---------------- CSR build ----------------
__global__ void k_count(const int* __restrict__ idx, int n, int* __restrict__ cnt) {
  int i = blockIdx.x * blockDim.x + threadIdx.x;
  if (i < n) atomicAdd(&cnt[idx[i]], 1);
}

__global__ __launch_bounds__(1024) void k_scan_excl(const int* __restrict__ in, int n,
                                                    int* __restrict__ out, int* __restrict__ cur) {
  __shared__ int wbase[16];
  __shared__ int chunk_tot;
  int tid = threadIdx.x;
  int lane = tid & 63;
  int w = tid >> 6;
  int carry = 0;
  for (int base = 0; base < n; base += 4096) {
    int i0 = base + tid * 4;
    int v[4];
#pragma unroll
    for (int j = 0; j < 4; j++) v[j] = (i0 + j < n) ? in[i0 + j] : 0;
    int x = v[0] + v[1] + v[2] + v[3];
    int incl = x;
#pragma unroll
    for (int off = 1; off < 64; off <<= 1) {
      int t = __shfl_up(incl, off);
      if (lane >= off) incl += t;
    }
    if (lane == 63) wbase[w] = incl;
    __syncthreads();
    if (w == 0) {
      int t = (lane < 16) ? wbase[lane] : 0;
      int it = t;
#pragma unroll
      for (int off = 1; off < 16; off <<= 1) {
        int v2 = __shfl_up(it, off);
        if (lane >= off) it += v2;
      }
      if (lane < 16) wbase[lane] = it - t;
      if (lane == 15) chunk_tot = it;
    }
    __syncthreads();
    int run = carry + wbase[w] + (incl - x);
#pragma unroll
    for (int j = 0; j < 4; j++) {
      if (i0 + j < n) {
        out[i0 + j] = run;
        if (cur) cur[i0 + j] = run;
      }
      run += v[j];
    }
    carry += chunk_tot;
    __syncthreads();
  }
  if (tid == 0) out[n] = carry;
}

__global__ void k_scatter(const int* __restrict__ src, const int* __restrict__ dst, int n,
                          int* __restrict__ cursor, int* __restrict__ dst_sorted) {
  int e = blockIdx.x * blockDim.x + threadIdx.x;
  if (e < n) {
    int s = src[e];
    int slot = atomicAdd(&cursor[s], 1);
    dst_sorted[slot] = dst[e];
  }
}

// gptr[g] = lower_bound(batch, g)
__global__ void k_gptr(const int* __restrict__ batch, int* __restrict__ gptr) {
  int g = blockIdx.x * blockDim.x + threadIdx.x;
  if (g > GG) return;
  int lo = 0, hi = NN;
  while (lo < hi) {
    int mid = (lo + hi) >> 1;
    if (batch[mid] < g) lo = mid + 1; else hi = mid;
  }
  gptr[g] = lo;
}

// ---------------- shared MFMA pieces ----------------
#define MF_TANH 1
#define MF_T 2
#define MF_P 4

__device__ __forceinline__ void afrag_from_f32(const float* xv, u32* ahw, u32* alw) {
#pragma unroll
  for (int p = 0; p < 4; p++) {
    u32 h0 = bf16r(xv[2 * p]), h1 = bf16r(xv[2 * p + 1]);
    float f0 = __uint_as_float(h0 << 16), f1 = __uint_as_float(h1 << 16);
    ahw[p] = h0 | (h1 << 16);
    alw[p] = bf16r(xv[2 * p] - f0) | (bf16r(xv[2 * p + 1] - f1) << 16);
  }
}

// epilogue: D layout col = t*16+ml, row = m0+quad*4+r. Pb row-stride 128, Pt stride 2.
template <int MODE>
__device__ __forceinline__ void epilogue(f32x4* acc, const float* __restrict__ bias,
                                         u32* __restrict__ To, u32* __restrict__ Pb,
                                         float* __restrict__ Pt, const float* __restrict__ cptr,
                                         int m0, int quad, int ml, int M) {
  float bj[8];
#pragma unroll
  for (int t = 0; t < 8; t++) {
    int col = t * 16 + ml;
    bj[t] = (bias != nullptr && col < DD) ? bias[col] : 0.f;
  }
  float cc = 1.f, sc = 1.f;
  if (MODE & MF_P) {
    cc = *cptr;
    sc = sqrtf(cc);
  }
#pragma unroll
  for (int r = 0; r < 4; r++) {
    int rowD = m0 + quad * 4 + r;
    float vs[8];
#pragma unroll
    for (int t = 0; t < 8; t++) {
      float v = acc[t][r] + bj[t];
      if (MODE & MF_TANH) {
        float e = exp2f(v * 2.8853900817779268f);  // exp(2v)
        v = 1.f - 2.f / (e + 1.f);
      }
      vs[t] = v;
    }
    if ((MODE & MF_T) && rowD < M) {
      u32* to = To + (size_t)rowD * 128 + ml;
#pragma unroll
      for (int t = 0; t < 8; t++) to[t * 16] = packhl(vs[t]);
    }
    if (MODE & MF_P) {
      float ps = 0.f;
#pragma unroll
      for (int t = 0; t < 8; t++) ps += vs[t] * vs[t];
#pragma unroll
      for (int off = 1; off < 16; off <<= 1) ps += __shfl_xor(ps, off);
      float nn = fmaxf(sqrtf(ps), 1e-9f);
      float e = expf(nn / sc);
      float f = sc * (e - 1.f / e) * 0.5f / nn;  // sc*sinh(nn/sc)/nn
      float tt = sqrtf(cc + f * f * ps);
      if (rowD < M) {
        u32* pb = Pb + (size_t)rowD * 128 + ml;
#pragma unroll
        for (int t = 0; t < 4; t++)
          pb[t * 16] = bf16r(f * vs[t]) | (bf16r(f * vs[t + 4]) << 16);
        if (ml == 0) Pt[rowD * 2] = tt;
      }
    }
  }
}

// ---------------- split-bf16 MFMA GEMM (single) ----------------
template <int MODE, int AF32>
__global__ __launch_bounds__(256) void k_mgemm(const float* __restrict__ Af,
                                               const u32* __restrict__ A32,
                                               const u16* __restrict__ Wfh,
                                               const u16* __restrict__ Wfl,
                                               const float* __restrict__ bias,
                                               u32* __restrict__ To, u32* __restrict__ Pb,
                                               float* __restrict__ Pt,
                                               const float* __restrict__ cptr, int M) {
  constexpr int NCH = AF32 ? 7 : 4;
  int lane = threadIdx.x & 63, wid = threadIdx.x >> 6;
  int m0 = blockIdx.x * 64 + wid * 16;
  int ml = lane & 15;
  int mld = m0 + ml;
  int quad = lane >> 4;
  f32x4 acc[8];
#pragma unroll
  for (int t = 0; t < 8; t++) acc[t] = (f32x4){0.f, 0.f, 0.f, 0.f};
#pragma unroll
  for (int q = 0; q < NCH; q++) {
    int k0 = q * 32 + quad * 8;
    union {
      short8 v;
      u32 w[4];
    } ah, al;
    if (AF32) {
      bool ok = (mld < M) && (k0 + 7 < IN_F);
      const float* ap = Af + (size_t)mld * IN_F + k0;
      float4 x0 = ok ? *(const float4*)ap : make_float4(0.f, 0.f, 0.f, 0.f);
      float4 x1 = ok ? *(const float4*)(ap + 4) : make_float4(0.f, 0.f, 0.f, 0.f);
      float xv[8] = {x0.x, x0.y, x0.z, x0.w, x1.x, x1.y, x1.z, x1.w};
      afrag_from_f32(xv, ah.w, al.w);
    } else {
      const u32* ap = A32 + (size_t)mld * 128 + k0;
      uint4 u0 = *(const uint4*)ap;
      uint4 u1 = *(const uint4*)(ap + 4);
      u32 uu[8] = {u0.x, u0.y, u0.z, u0.w, u1.x, u1.y, u1.z, u1.w};
#pragma unroll
      for (int p = 0; p < 4; p++) {
        ah.w[p] = __builtin_amdgcn_perm(uu[2 * p + 1], uu[2 * p], 0x05040100u);
        al.w[p] = __builtin_amdgcn_perm(uu[2 * p + 1], uu[2 * p], 0x07060302u);
      }
    }
    const u16* bph = Wfh + ((size_t)(q * 8) * 64 + lane) * 8;
    const u16* bpl = Wfl + ((size_t)(q * 8) * 64 + lane) * 8;
#pragma unroll
    for (int t = 0; t < 8; t++) {
      short8 bh = *(const short8*)(bph + t * 512);
      short8 bl = *(const short8*)(bpl + t * 512);
      acc[t] = __builtin_amdgcn_mfma_f32_16x16x32_bf16(ah.v, bh, acc[t], 0, 0, 0);
      acc[t] = __builtin_amdgcn_mfma_f32_16x16x32_bf16(al.v, bh, acc[t], 0, 0, 0);
      acc[t] = __builtin_amdgcn_mfma_f32_16x16x32_bf16(ah.v, bl, acc[t], 0, 0, 0);
    }
  }
  epilogue<MODE>(acc, bias, To, Pb, Pt, cptr, m0, quad, ml, M);
}

// ---------------- fused MLP pair: GEMM(Wa)+tanh -> LDS transpose -> GEMM(Wb)+tanh+epi ----------------
template <int MODE>
__global__ __launch_bounds__(256) void k_mgemm_mlp(const u32* __restrict__ A32,
                                                   const u16* __restrict__ Wha,
                                                   const u16* __restrict__ Wla,
                                                   const float* __restrict__ ba,
                                                   const u16* __restrict__ Whb,
                                                   const u16* __restrict__ Wlb,
                                                   const float* __restrict__ bb,
                                                   u32* __restrict__ To, u32* __restrict__ Pb,
                                                   float* __restrict__ Pt,
                                                   const float* __restrict__ cptr, int M) {
  __shared__ float tile[4][16][129];
  int lane = threadIdx.x & 63, wid = threadIdx.x >> 6;
  int m0 = blockIdx.x * 64 + wid * 16;
  int ml = lane & 15;
  int mld = m0 + ml;
  int quad = lane >> 4;
  f32x4 acc[8];
#pragma unroll
  for (int t = 0; t < 8; t++) acc[t] = (f32x4){0.f, 0.f, 0.f, 0.f};
  // GEMM 1 (A from global packhl)
#pragma unroll
  for (int q = 0; q < 4; q++) {
    int k0 = q * 32 + quad * 8;
    union {
      short8 v;
      u32 w[4];
    } ah, al;
    const u32* ap = A32 + (size_t)mld * 128 + k0;
    uint4 u0 = *(const uint4*)ap;
    uint4 u1 = *(const uint4*)(ap + 4);
    u32 uu[8] = {u0.x, u0.y, u0.z, u0.w, u1.x, u1.y, u1.z, u1.w};
#pragma unroll
    for (int p = 0; p < 4; p++) {
      ah.w[p] = __builtin_amdgcn_perm(uu[2 * p + 1], uu[2 * p], 0x05040100u);
      al.w[p] = __builtin_amdgcn_perm(uu[2 * p + 1], uu[2 * p], 0x07060302u);
    }
    const u16* bph = Wha + ((size_t)(q * 8) * 64 + lane) * 8;
    const u16* bpl = Wla + ((size_t)(q * 8) * 64 + lane) * 8;
#pragma unroll
    for (int t = 0; t < 8; t++) {
      short8 bh = *(const short8*)(bph + t * 512);
      short8 bl = *(const short8*)(bpl + t * 512);
      acc[t] = __builtin_amdgcn_mfma_f32_16x16x32_bf16(ah.v, bh, acc[t], 0, 0, 0);
      acc[t] = __builtin_amdgcn_mfma_f32_16x16x32_bf16(al.v, bh, acc[t], 0, 0, 0);
      acc[t] = __builtin_amdgcn_mfma_f32_16x16x32_bf16(ah.v, bl, acc[t], 0, 0, 0);
    }
  }
  // epi1: +bias, tanh, write C-layout into per-wave LDS tile
  {
    float bj[8];
#pragma unroll
    for (int t = 0; t < 8; t++) {
      int col = t * 16 + ml;
      bj[t] = (col < DD) ? ba[col] : 0.f;
    }
#pragma unroll
    for (int r = 0; r < 4; r++) {
#pragma unroll
      for (int t = 0; t < 8; t++) {
        float v = acc[t][r] + bj[t];
        float e = exp2f(v * 2.8853900817779268f);
        v = 1.f - 2.f / (e + 1.f);
        tile[wid][quad * 4 + r][t * 16 + ml] = v;
      }
    }
  }
  __syncthreads();
  // GEMM 2 (A from LDS fp32)
#pragma unroll
  for (int t = 0; t < 8; t++) acc[t] = (f32x4){0.f, 0.f, 0.f, 0.f};
#pragma unroll
  for (int q = 0; q < 4; q++) {
    int k0 = q * 32 + quad * 8;
    float xv[8];
#pragma unroll
    for (int j = 0; j < 8; j++) xv[j] = tile[wid][ml][k0 + j];
    union {
      short8 v;
      u32 w[4];
    } ah, al;
    afrag_from_f32(xv, ah.w, al.w);
    const u16* bph = Whb + ((size_t)(q * 8) * 64 + lane) * 8;
    const u16* bpl = Wlb + ((size_t)(q * 8) * 64 + lane) * 8;
#pragma unroll
    for (int t = 0; t < 8; t++) {
      short8 bh = *(const short8*)(bph + t * 512);
      short8 bl = *(const short8*)(bpl + t * 512);
      acc[t] = __builtin_amdgcn_mfma_f32_16x16x32_bf16(ah.v, bh, acc[t], 0, 0, 0);
      acc[t] = __builtin_amdgcn_mfma_f32_16x16x32_bf16(al.v, bh, acc[t], 0, 0, 0);
      acc[t] = __builtin_amdgcn_mfma_f32_16x16x32_bf16(ah.v, bl, acc[t], 0, 0, 0);
    }
  }
  epilogue<MODE>(acc, bb, To, Pb, Pt, cptr, m0, quad, ml, M);
}

// ---------------- fused attention + aggregation, quarter-wave ----------------
// HHb row (128 u32): [0..63] HL bf16 pairs (cols i, i+64), [64..127] H bf16 pairs.
// ptHH[node] = (time(HL), time(H)).
__global__ void k_agg_q(const u32* __restrict__ HHb, const float2* __restrict__ ptHH,
                        const u32* __restrict__ T, const int* __restrict__ rowp,
                        const int* __restrict__ dsts, const float* __restrict__ epsp,
                        const float* __restrict__ cptr, u32* __restrict__ Tout, int n) {
  int node = blockIdx.x * 4 + (threadIdx.x >> 6);
  int lane = threadIdx.x & 63;
  if (node >= n) return;
  int p = lane & 15;
  int q = lane >> 4;
  float c = *cptr, sc = sqrtf(c), rcpc = 1.f / c;
  float eps = *epsp;
  uint4 a4 = *(const uint4*)(HHb + (size_t)node * 128 + p * 4);
  float alo[4], ahi[4];
  {
    u32 aw[4] = {a4.x, a4.y, a4.z, a4.w};
#pragma unroll
    for (int j = 0; j < 4; j++) {
      alo[j] = __uint_as_float(aw[j] << 16);
      ahi[j] = __uint_as_float(aw[j] & 0xffff0000u);
    }
  }
  float pts = ptHH[node].x;
  int e0 = rowp[node], e1 = rowp[node + 1];
  int iters = (e1 - e0 + 3) >> 2;
  float m[8] = {0.f, 0.f, 0.f, 0.f, 0.f, 0.f, 0.f, 0.f};
  float mt = 0.f;
#pragma unroll 2
  for (int it = 0; it < iters; it++) {
    int e = e0 + it * 4 + q;
    bool ve = e < e1;
    int ei = ve ? e : e0;
    int d = dsts[ei];
    const u32* rb = HHb + (size_t)d * 128 + p * 4;
    uint4 b4 = *(const uint4*)rb;
    uint4 h4 = *(const uint4*)(rb + 64);
    float2 pp = ptHH[d];
    u32 bw[4] = {b4.x, b4.y, b4.z, b4.w};
    float dot = 0.f;
#pragma unroll
    for (int j = 0; j < 4; j++) {
      dot = fmaf(alo[j], __uint_as_float(bw[j] << 16), dot);
      dot = fmaf(ahi[j], __uint_as_float(bw[j] & 0xffff0000u), dot);
    }
#pragma unroll
    for (int off = 1; off < 16; off <<= 1) dot += __shfl_xor(dot, off);
    float valv = fmaxf((pts * pp.x - dot) * rcpc, 1.f + EPSH);
    float w = valv + sqrtf(fmaf(valv, valv, -1.f));
    float att = exp2f(-sc * __log2f(w));
    att = ve ? att : 0.f;
    u32 hw[4] = {h4.x, h4.y, h4.z, h4.w};
#pragma unroll
    for (int j = 0; j < 4; j++) {
      m[j] = fmaf(att, __uint_as_float(hw[j] << 16), m[j]);
      m[4 + j] = fmaf(att, __uint_as_float(hw[j] & 0xffff0000u), m[4 + j]);
    }
    mt = fmaf(att, pp.y, mt);
  }
#pragma unroll
  for (int j = 0; j < 8; j++) {
    m[j] += __shfl_xor(m[j], 16);
    m[j] += __shfl_xor(m[j], 32);
  }
  mt += __shfl_xor(mt, 16);
  mt += __shfl_xor(mt, 32);
  float lp = 0.f;
#pragma unroll
  for (int j = 0; j < 8; j++) lp = fmaf(m[j], m[j], lp);
#pragma unroll
  for (int off = 1; off < 16; off <<= 1) lp += __shfl_xor(lp, off);
  float lsq = lp;
  float neg_inner = mt * mt - lsq;
  float denom = sqrtf(fmaxf(neg_inner, 1e-9f));
  float r = sc / denom;
  float ssq = r * r * lsq;
  float agg0 = sqrtf(c + ssq);
  float ynA = fmaxf(sqrtf(ssq), 1e-9f);
  float v2 = fmaxf(agg0 / sc, 1.f + EPSH);
  float dA = sc * 0.69314718056f * __log2f(v2 + sqrtf(v2 * v2 - 1.f));
  float sca = dA * r / ynA;
  uint4 t0 = *(const uint4*)(T + (size_t)node * 128 + p * 4);
  uint4 t1 = *(const uint4*)(T + (size_t)node * 128 + 64 + p * 4);
  u32 tw0[4] = {t0.x, t0.y, t0.z, t0.w};
  u32 tw1[4] = {t1.x, t1.y, t1.z, t1.w};
  float oe = 1.f + eps;
  uint4 o0, o1;
  u32* po0 = (u32*)&o0;
  u32* po1 = (u32*)&o1;
#pragma unroll
  for (int j = 0; j < 4; j++) {
    po0[j] = packhl(fmaf(sca, m[j], oe * rec(tw0[j])));
    po1[j] = packhl(fmaf(sca, m[4 + j], oe * rec(tw1[j])));
  }
  if (q == 0) {
    *(uint4*)(Tout + (size_t)node * 128 + p * 4) = o0;
    *(uint4*)(Tout + (size_t)node * 128 + 64 + p * 4) = o1;
  }
}

// ---------------- pooling ----------------
__global__ void k_pool(const u32* __restrict__ U, const int* __restrict__ gptr,
                       float* __restrict__ out, int layer) {
  int g = blockIdx.x;
  int c = threadIdx.x;  // 0..127
  int s = gptr[g], e = gptr[g + 1];
  float acc = 0.f;
  if (c > 0) {
    const u32* up = U + (c - 1);
    int i = s;
    float a0 = 0.f, a1 = 0.f, a2 = 0.f, a3 = 0.f;
    for (; i + 3 < e; i += 4) {
      a0 += rec(up[(size_t)i * 128]);
      a1 += rec(up[(size_t)(i + 1) * 128]);
      a2 += rec(up[(size_t)(i + 2) * 128]);
      a3 += rec(up[(size_t)(i + 3) * 128]);
    }
    for (; i < e; i++) a0 += rec(up[(size_t)i * 128]);
    acc = (a0 + a1) + (a2 + a3);
  }
  out[(size_t)g * 256 + layer * 128 + c] = acc;
}

// ---------------- launch ----------------
extern "C" void kernel_launch(void* const* d_in, const int* in_sizes, int n_in, void* d_out,
                              int out_size, void* d_ws, size_t ws_size, hipStream_t stream) {
  const float* x = (const float*)d_in[0];
  const float* cptr = (const float*)d_in[1];
  const float* w_in = (const float*)d_in[2];
  const float* att_w = (const float*)d_in[3];
  const float* att_b = (const float*)d_in[4];
  const float* epsv = (const float*)d_in[5];
  const float* mlp_w = (const float*)d_in[6];
  const float* mlp_b = (const float*)d_in[7];
  const int* ei = (const int*)d_in[8];
  const int* batch = (const int*)d_in[9];
  const int* srcp = ei;
  const int* dstp = ei + EE;
  float* out = (float*)d_out;

  u32* ws = (u32*)d_ws;
  u16* Wfh = (u16*)ws;             // WF_TOT u16
  u16* Wfl = Wfh + WF_TOT;
  int* deg = (int*)(ws + 126976);  // N
  int* rowp = deg + NN;            // N+1
  int* cursor = rowp + NN + 1;     // N
  int* gptr = cursor + NN;         // G+1
  int* dsts = gptr + GG + 1;       // E
  size_t o1 = (size_t)((u32*)(dsts + EE) - ws);
  o1 = (o1 + 3) & ~(size_t)3;
  float2* ptHH = (float2*)(ws + o1);              // NNP float2
  u32* HHb = ws + o1 + 2 * NNP;                   // NNP*128 (HL | H)
  u32* A32 = HHb + (size_t)NNP * 128;             // NNP*128
  u32* B32 = A32 + (size_t)NNP * 128;             // NNP*128

  const int EW = 12500;  // agg: 4 nodes/block
  const int GEMMG = (NN + 63) / 64;

  hipMemsetAsync(deg, 0, NN * sizeof(int), stream);
  k_prep_wf<<<64, 256, 0, stream>>>(att_w, mlp_w, w_in, Wfh, Wfl);
  k_count<<<(EE + 255) / 256, 256, 0, stream>>>(srcp, EE, deg);
  k_gptr<<<3, 256, 0, stream>>>(batch, gptr);
  k_scan_excl<<<1, 1024, 0, stream>>>(deg, NN, rowp, cursor);
  k_scatter<<<(EE + 255) / 256, 256, 0, stream>>>(srcp, dstp, EE, cursor, dsts);

#define WH(m) (Wfh + 28672 + (m) * 16384)
#define WL(m) (Wfl + 28672 + (m) * 16384)
  float* ptX = (float*)ptHH;  // .x at stride 2; .y at +1

  // input: T0 -> A32 ; H point -> (HHb+64, ptHH.y)
  k_mgemm<MF_T | MF_P, 1><<<GEMMG, 256, 0, stream>>>(x, nullptr, Wfh, Wfl, nullptr, A32,
                                                     HHb + 64, ptX + 1, cptr, NN);

  // ---- layer 0 ----
  k_mgemm<MF_P, 0><<<GEMMG, 256, 0, stream>>>(nullptr, A32, WH(0), WL(0), att_b, nullptr, HHb,
                                              ptX, cptr, NN);
  k_agg_q<<<EW, 256, 0, stream>>>(HHb, ptHH, A32, rowp, dsts, epsv + 0, cptr, B32, NN);
  k_mgemm_mlp<MF_TANH | MF_T | MF_P><<<GEMMG, 256, 0, stream>>>(
      B32, WH(2), WL(2), mlp_b + 0 * DD, WH(3), WL(3), mlp_b + 1 * DD, A32, HHb + 64, ptX + 1,
      cptr, NN);
  k_pool<<<GG, 128, 0, stream>>>(A32, gptr, out, 0);

  // ---- layer 1 ----
  k_mgemm<MF_P, 0><<<GEMMG, 256, 0, stream>>>(nullptr, A32, WH(1), WL(1), att_b + DD, nullptr,
                                              HHb, ptX, cptr, NN);
  k_agg_q<<<EW, 256, 0, stream>>>(HHb, ptHH, A32, rowp, dsts, epsv + 1, cptr, B32, NN);
  k_mgemm_mlp<MF_TANH | MF_T><<<GEMMG, 256, 0, stream>>>(B32, WH(4), WL(4), mlp_b + 2 * DD,
                                                         WH(5), WL(5), mlp_b + 3 * DD, B32,
                                                         nullptr, nullptr, cptr, NN);
  k_pool<<<GG, 128, 0, stream>>>(B32, gptr, out, 1);
}

// Round 8
// 522.145 us; speedup vs baseline: 2.8168x; 1.0477x over previous
//
#include <hip/hip_runtime.h>
#include <hip/hip_fp16.h>
#include <math.h>

#define NN 50000
#define NNP 50048
#define EE 800000
#define IN_F 200
#define DD 127
#define GG 512
#define EPSH 1e-5f
#define PS_SCALE 0.015625f  // 2^-6 pre-scale on H points (centroid is scale-invariant)

typedef unsigned int u32;
typedef unsigned short u16;
typedef __attribute__((ext_vector_type(8))) short short8;
typedef __attribute__((ext_vector_type(4))) float f32x4;
typedef _Float16 h2f __attribute__((ext_vector_type(2)));
typedef __fp16 fp16x2 __attribute__((ext_vector_type(2)));
union UH {
  u32 u;
  h2f h;
  fp16x2 f;
};

__device__ __forceinline__ u32 bf16r(float x) {
  u32 u = __float_as_uint(x);
  return (u + 0x7fffu + ((u >> 16) & 1u)) >> 16;
}

__device__ __forceinline__ u32 packhl(float v) {  // u32 = bf16_hi | bf16_lo<<16
  u32 hi = bf16r(v);
  float vh = __uint_as_float(hi << 16);
  u32 lo = bf16r(v - vh);
  return hi | (lo << 16);
}

__device__ __forceinline__ float rec(u32 u) {
  return __uint_as_float(u << 16) + __uint_as_float(u & 0xffff0000u);
}

__device__ __forceinline__ u32 pk2h(float a, float b) {  // packed half2 bits
#if __has_builtin(__builtin_amdgcn_cvt_pkrtz)
  UH x;
  x.f = __builtin_amdgcn_cvt_pkrtz(a, b);
  return x.u;
#else
  __half2 r = __floats2half2_rn(a, b);
  return *(u32*)&r;
#endif
}

__device__ __forceinline__ float fdot2h(u32 a, u32 b, float acc) {
  UH ua, ub;
  ua.u = a;
  ub.u = b;
#if __has_builtin(__builtin_amdgcn_fdot2)
  return __builtin_amdgcn_fdot2(ua.h, ub.h, acc, false);
#else
  acc = fmaf((float)ua.h[0], (float)ub.h[0], acc);
  return fmaf((float)ua.h[1], (float)ub.h[1], acc);
#endif
}

// ---------------- prep: weights -> bf16 hi/lo fragment layout ----------------
#define WF_TOT (28672 + 6 * 16384)
__global__ void k_prep_wf(const float* __restrict__ att_w, const float* __restrict__ mlp_w,
                          const float* __restrict__ w_in, u16* __restrict__ Wfh,
                          u16* __restrict__ Wfl) {
  for (int idx = blockIdx.x * 256 + threadIdx.x; idx < WF_TOT; idx += gridDim.x * 256) {
    float val;
    if (idx < 28672) {
      int q = idx >> 12, rem = idx & 4095;
      int t = rem >> 9, l = (rem >> 3) & 63, j = rem & 7;
      int k = q * 32 + ((l >> 4) << 3) + j, n = t * 16 + (l & 15);
      val = (k < IN_F && n < DD) ? w_in[k * DD + n] : 0.f;
    } else {
      int rel = idx - 28672;
      int mat = rel >> 14, rem = rel & 16383;
      int q = rem >> 12;
      rem &= 4095;
      int t = rem >> 9, l = (rem >> 3) & 63, j = rem & 7;
      int k = q * 32 + ((l >> 4) << 3) + j, n = t * 16 + (l & 15);
      const float* wsrc = (mat < 2) ? att_w + mat * DD * DD : mlp_w + (mat - 2) * DD * DD;
      val = (k < DD && n < DD) ? wsrc[n * DD + k] : 0.f;
    }
    u32 hi = bf16r(val);
    float vh = __uint_as_float(hi << 16);
    u32 lo = bf16r(val - vh);
    Wfh[idx] = (u16)hi;
    Wfl[idx] = (u16)lo;
  }
}

// ---------------- CSR build ----------------
__global__ void k_count(const int* __restrict__ idx, int n, int* __restrict__ cnt) {
  int i = blockIdx.x * blockDim.x + threadIdx.x;
  if (i < n) atomicAdd(&cnt[idx[i]], 1);
}

__global__ __launch_bounds__(1024) void k_scan_excl(const int* __restrict__ in, int n,
                                                    int* __restrict__ out, int* __restrict__ cur) {
  __shared__ int wbase[16];
  __shared__ int chunk_tot;
  int tid = threadIdx.x;
  int lane = tid & 63;
  int w = tid >> 6;
  int carry = 0;
  for (int base = 0; base < n; base += 4096) {
    int i0 = base + tid * 4;
    int v[4];
#pragma unroll
    for (int j = 0; j < 4; j++) v[j] = (i0 + j < n) ? in[i0 + j] : 0;
    int x = v[0] + v[1] + v[2] + v[3];
    int incl = x;
#pragma unroll
    for (int off = 1; off < 64; off <<= 1) {
      int t = __shfl_up(incl, off);
      if (lane >= off) incl += t;
    }
    if (lane == 63) wbase[w] = incl;
    __syncthreads();
    if (w == 0) {
      int t = (lane < 16) ? wbase[lane] : 0;
      int it = t;
#pragma unroll
      for (int off = 1; off < 16; off <<= 1) {
        int v2 = __shfl_up(it, off);
        if (lane >= off) it += v2;
      }
      if (lane < 16) wbase[lane] = it - t;
      if (lane == 15) chunk_tot = it;
    }
    __syncthreads();
    int run = carry + wbase[w] + (incl - x);
#pragma unroll
    for (int j = 0; j < 4; j++) {
      if (i0 + j < n) {
        out[i0 + j] = run;
        if (cur) cur[i0 + j] = run;
      }
      run += v[j];
    }
    carry += chunk_tot;
    __syncthreads();
  }
  if (tid == 0) out[n] = carry;
}

__global__ void k_scatter(const int* __restrict__ src, const int* __restrict__ dst, int n,
                          int* __restrict__ cursor, int* __restrict__ dst_sorted) {
  int e = blockIdx.x * blockDim.x + threadIdx.x;
  if (e < n) {
    int s = src[e];
    int slot = atomicAdd(&cursor[s], 1);
    dst_sorted[slot] = dst[e];
  }
}

__global__ void k_gptr(const int* __restrict__ batch, int* __restrict__ gptr) {
  int g = blockIdx.x * blockDim.x + threadIdx.x;
  if (g > GG) return;
  int lo = 0, hi = NN;
  while (lo < hi) {
    int mid = (lo + hi) >> 1;
    if (batch[mid] < g) lo = mid + 1; else hi = mid;
  }
  gptr[g] = lo;
}

// ---------------- MFMA building blocks ----------------
union AB {
  short8 v;
  u32 w[4];
};

__device__ __forceinline__ void build_hl(const float* xv, AB& ah, AB& al) {
#pragma unroll
  for (int p = 0; p < 4; p++) {
    u32 h0 = bf16r(xv[2 * p]), h1 = bf16r(xv[2 * p + 1]);
    float f0 = __uint_as_float(h0 << 16), f1 = __uint_as_float(h1 << 16);
    ah.w[p] = h0 | (h1 << 16);
    al.w[p] = bf16r(xv[2 * p] - f0) | (bf16r(xv[2 * p + 1] - f1) << 16);
  }
}

__device__ __forceinline__ void mfma3(const AB& ah, const AB& al, const u16* __restrict__ Wh,
                                      const u16* __restrict__ Wl, int q, int lane, f32x4* acc) {
  const u16* bph = Wh + ((size_t)(q * 8) * 64 + lane) * 8;
  const u16* bpl = Wl + ((size_t)(q * 8) * 64 + lane) * 8;
#pragma unroll
  for (int t = 0; t < 8; t++) {
    short8 bh = *(const short8*)(bph + t * 512);
    short8 bl = *(const short8*)(bpl + t * 512);
    acc[t] = __builtin_amdgcn_mfma_f32_16x16x32_bf16(ah.v, bh, acc[t], 0, 0, 0);
    acc[t] = __builtin_amdgcn_mfma_f32_16x16x32_bf16(al.v, bh, acc[t], 0, 0, 0);
    acc[t] = __builtin_amdgcn_mfma_f32_16x16x32_bf16(ah.v, bl, acc[t], 0, 0, 0);
  }
}

__device__ __forceinline__ void gemm_packhl(const u32* __restrict__ A32, int mld,
                                            const u16* __restrict__ Wh,
                                            const u16* __restrict__ Wl, int lane, int quad,
                                            f32x4* acc) {
#pragma unroll
  for (int q = 0; q < 4; q++) {
    int k0 = q * 32 + quad * 8;
    const u32* ap = A32 + (size_t)mld * 128 + k0;
    uint4 u0 = *(const uint4*)ap;
    uint4 u1 = *(const uint4*)(ap + 4);
    u32 uu[8] = {u0.x, u0.y, u0.z, u0.w, u1.x, u1.y, u1.z, u1.w};
    AB ah, al;
#pragma unroll
    for (int p = 0; p < 4; p++) {
      ah.w[p] = __builtin_amdgcn_perm(uu[2 * p + 1], uu[2 * p], 0x05040100u);
      al.w[p] = __builtin_amdgcn_perm(uu[2 * p + 1], uu[2 * p], 0x07060302u);
    }
    mfma3(ah, al, Wh, Wl, q, lane, acc);
  }
}

__device__ __forceinline__ void gemm_lds(const float (*tile)[129], int ml, int quad, int lane,
                                         const u16* __restrict__ Wh, const u16* __restrict__ Wl,
                                         f32x4* acc) {
#pragma unroll
  for (int q = 0; q < 4; q++) {
    int k0 = q * 32 + quad * 8;
    float xv[8];
#pragma unroll
    for (int j = 0; j < 8; j++) xv[j] = tile[ml][k0 + j];
    AB ah, al;
    build_hl(xv, ah, al);
    mfma3(ah, al, Wh, Wl, q, lane, acc);
  }
}

__device__ __forceinline__ void bias8(const float* __restrict__ bias, int ml, float* bj) {
#pragma unroll
  for (int t = 0; t < 8; t++) {
    int col = t * 16 + ml;
    bj[t] = (bias != nullptr && col < DD) ? bias[col] : 0.f;
  }
}

template <int TANH>
__device__ __forceinline__ void row_vs(const f32x4* acc, const float* bj, int r, float* vs) {
#pragma unroll
  for (int t = 0; t < 8; t++) {
    float v = acc[t][r] + bj[t];
    if (TANH) {
      float e = exp2f(v * 2.8853900817779268f);  // exp(2v)
      v = 1.f - 2.f / (e + 1.f);
    }
    vs[t] = v;
  }
}

__device__ __forceinline__ void store_T_row(const float* vs, u32* __restrict__ To, int rowD,
                                            int ml) {
  u32* to = To + (size_t)rowD * 128 + ml;
#pragma unroll
  for (int t = 0; t < 8; t++) to[t * 16] = packhl(vs[t]);
}

// point store: slot s=t*16+ml holds half2(spatial col s, col s+64); time -> Pt[rowD*2]
__device__ __forceinline__ void store_P_row(const float* vs, u32* __restrict__ Pb,
                                            float* __restrict__ Pt, int rowD, int ml, float cc,
                                            float sc, float pscale) {
  float ps = 0.f;
#pragma unroll
  for (int t = 0; t < 8; t++) ps += vs[t] * vs[t];
#pragma unroll
  for (int off = 1; off < 16; off <<= 1) ps += __shfl_xor(ps, off);
  float nn = fmaxf(sqrtf(ps), 1e-9f);
  float e = expf(nn / sc);
  float f = sc * (e - 1.f / e) * 0.5f / nn;  // sc*sinh(nn/sc)/nn
  float tt = sqrtf(cc + f * f * ps);
  f *= pscale;
  u32* pb = Pb + (size_t)rowD * 128 + ml;
#pragma unroll
  for (int t = 0; t < 4; t++) pb[t * 16] = pk2h(f * vs[t], f * vs[t + 4]);
  if (ml == 0) Pt[rowD * 2] = pscale * tt;
}

// ---------------- fused input GEMM + att-GEMM(layer0) ----------------
__global__ __launch_bounds__(256) void k_gemm_in(
    const float* __restrict__ x, const u16* __restrict__ WhI, const u16* __restrict__ WlI,
    const u16* __restrict__ WhA, const u16* __restrict__ WlA, const float* __restrict__ attb,
    u32* __restrict__ To, u32* __restrict__ HHh, float* __restrict__ ptF,
    const float* __restrict__ cptr, int M) {
  __shared__ float tile[4][16][129];
  int lane = threadIdx.x & 63, wid = threadIdx.x >> 6;
  int m0 = blockIdx.x * 64 + wid * 16;
  int ml = lane & 15, quad = lane >> 4;
  int mld = m0 + ml;
  f32x4 acc[8];
#pragma unroll
  for (int t = 0; t < 8; t++) acc[t] = (f32x4){0.f, 0.f, 0.f, 0.f};
#pragma unroll
  for (int q = 0; q < 7; q++) {
    int k0 = q * 32 + quad * 8;
    bool ok = (mld < M) && (k0 + 7 < IN_F);
    const float* ap = x + (size_t)mld * IN_F + k0;
    float4 x0 = ok ? *(const float4*)ap : make_float4(0.f, 0.f, 0.f, 0.f);
    float4 x1 = ok ? *(const float4*)(ap + 4) : make_float4(0.f, 0.f, 0.f, 0.f);
    float xv[8] = {x0.x, x0.y, x0.z, x0.w, x1.x, x1.y, x1.z, x1.w};
    AB ah, al;
    build_hl(xv, ah, al);
    mfma3(ah, al, WhI, WlI, q, lane, acc);
  }
  float cc = *cptr, sc = sqrtf(cc);
  {
    float bj[8];
    bias8(nullptr, ml, bj);
#pragma unroll
    for (int r = 0; r < 4; r++) {
      int rowD = m0 + quad * 4 + r;
      float vs[8];
      row_vs<0>(acc, bj, r, vs);
      if (rowD < M) {
        store_T_row(vs, To, rowD, ml);
        store_P_row(vs, HHh + 64, ptF + 1, rowD, ml, cc, sc, PS_SCALE);
      }
#pragma unroll
      for (int t = 0; t < 8; t++) tile[wid][quad * 4 + r][t * 16 + ml] = vs[t];
    }
  }
#pragma unroll
  for (int t = 0; t < 8; t++) acc[t] = (f32x4){0.f, 0.f, 0.f, 0.f};
  gemm_lds(tile[wid], ml, quad, lane, WhA, WlA, acc);
  {
    float bj[8];
    bias8(attb, ml, bj);
#pragma unroll
    for (int r = 0; r < 4; r++) {
      int rowD = m0 + quad * 4 + r;
      float vs[8];
      row_vs<0>(acc, bj, r, vs);
      if (rowD < M) store_P_row(vs, HHh, ptF, rowD, ml, cc, sc, 1.f);
    }
  }
}

// ---------------- fused MLP pair (+ next layer's att GEMM unless LAST) ----------------
template <int LAST>
__global__ __launch_bounds__(256) void k_mlp3(
    const u32* __restrict__ A32, const u16* __restrict__ Wha, const u16* __restrict__ Wla,
    const float* __restrict__ ba, const u16* __restrict__ Whb, const u16* __restrict__ Wlb,
    const float* __restrict__ bb, const u16* __restrict__ WhA, const u16* __restrict__ WlA,
    const float* __restrict__ attb, u32* __restrict__ To, u32* __restrict__ HHh,
    float* __restrict__ ptF, const float* __restrict__ cptr, int M) {
  __shared__ float tile[4][16][129];
  int lane = threadIdx.x & 63, wid = threadIdx.x >> 6;
  int m0 = blockIdx.x * 64 + wid * 16;
  int ml = lane & 15, quad = lane >> 4;
  int mld = m0 + ml;
  f32x4 acc[8];
#pragma unroll
  for (int t = 0; t < 8; t++) acc[t] = (f32x4){0.f, 0.f, 0.f, 0.f};
  gemm_packhl(A32, mld, Wha, Wla, lane, quad, acc);
  {
    float bj[8];
    bias8(ba, ml, bj);
#pragma unroll
    for (int r = 0; r < 4; r++) {
      float vs[8];
      row_vs<1>(acc, bj, r, vs);
#pragma unroll
      for (int t = 0; t < 8; t++) tile[wid][quad * 4 + r][t * 16 + ml] = vs[t];
    }
  }
#pragma unroll
  for (int t = 0; t < 8; t++) acc[t] = (f32x4){0.f, 0.f, 0.f, 0.f};
  gemm_lds(tile[wid], ml, quad, lane, Whb, Wlb, acc);
  float cc = 1.f, sc = 1.f;
  if (!LAST) {
    cc = *cptr;
    sc = sqrtf(cc);
  }
  {
    float bj[8];
    bias8(bb, ml, bj);
#pragma unroll
    for (int r = 0; r < 4; r++) {
      int rowD = m0 + quad * 4 + r;
      float vs[8];
      row_vs<1>(acc, bj, r, vs);
      if (rowD < M) store_T_row(vs, To, rowD, ml);
      if (!LAST) {
        if (rowD < M) store_P_row(vs, HHh + 64, ptF + 1, rowD, ml, cc, sc, PS_SCALE);
#pragma unroll
        for (int t = 0; t < 8; t++) tile[wid][quad * 4 + r][t * 16 + ml] = vs[t];
      }
    }
  }
  if (!LAST) {
#pragma unroll
    for (int t = 0; t < 8; t++) acc[t] = (f32x4){0.f, 0.f, 0.f, 0.f};
    gemm_lds(tile[wid], ml, quad, lane, WhA, WlA, acc);
    float bj[8];
    bias8(attb, ml, bj);
#pragma unroll
    for (int r = 0; r < 4; r++) {
      int rowD = m0 + quad * 4 + r;
      float vs[8];
      row_vs<0>(acc, bj, r, vs);
      if (rowD < M) store_P_row(vs, HHh, ptF, rowD, ml, cc, sc, 1.f);
    }
  }
}

// ---------------- fused attention + aggregation, 8-lane edge groups ----------------
// HHh row (128 u32): [0..63] HL half2 (cols s, s+64); [64..127] H half2 * 2^-6.
// ptHH[node] = (time(HL), time(H)*2^-6).
__global__ __launch_bounds__(256) void k_agg_o(const u32* __restrict__ HHh,
                                               const float2* __restrict__ ptHH,
                                               const u32* __restrict__ T,
                                               const int* __restrict__ rowp,
                                               const int* __restrict__ dsts,
                                               const float* __restrict__ epsp,
                                               const float* __restrict__ cptr,
                                               u32* __restrict__ Tout, int n) {
  int node = blockIdx.x * 4 + (threadIdx.x >> 6);
  int lane = threadIdx.x & 63;
  if (node >= n) return;
  int o = lane & 7, g = lane >> 3;
  float c = *cptr, sc = sqrtf(c), rcpc = 1.f / c;
  float eps = *epsp;
  const u32* arow = HHh + (size_t)node * 128 + o * 8;
  uint4 a0 = *(const uint4*)arow;
  uint4 a1 = *(const uint4*)(arow + 4);
  u32 apk[8] = {a0.x, a0.y, a0.z, a0.w, a1.x, a1.y, a1.z, a1.w};
  float pts = ptHH[node].x;
  int e0 = rowp[node], e1 = rowp[node + 1];
  int iters = (e1 - e0 + 7) >> 3;
  h2f mpk[8];
  {
    UH z;
    z.u = 0;
#pragma unroll
    for (int j = 0; j < 8; j++) mpk[j] = z.h;
  }
  float mt = 0.f;
#pragma unroll 2
  for (int it = 0; it < iters; it++) {
    int e = e0 + it * 8 + g;
    bool ve = e < e1;
    int d = dsts[ve ? e : e0];
    const u32* rb = HHh + (size_t)d * 128 + o * 8;
    uint4 b0 = *(const uint4*)rb;
    uint4 b1 = *(const uint4*)(rb + 4);
    uint4 h0 = *(const uint4*)(rb + 64);
    uint4 h1 = *(const uint4*)(rb + 68);
    float2 pp = ptHH[d];
    u32 bw[8] = {b0.x, b0.y, b0.z, b0.w, b1.x, b1.y, b1.z, b1.w};
    float dot = 0.f;
#pragma unroll
    for (int j = 0; j < 8; j++) dot = fdot2h(apk[j], bw[j], dot);
    dot += __shfl_xor(dot, 1);
    dot += __shfl_xor(dot, 2);
    dot += __shfl_xor(dot, 4);
    float valv = fmaxf((pts * pp.x - dot) * rcpc, 1.f + EPSH);
    float w = valv + sqrtf(fmaf(valv, valv, -1.f));
    float att = exp2f(-sc * __log2f(w));  // exp(-sc*acosh(val))
    att = ve ? att : 0.f;
    UH att2;
    att2.u = pk2h(att, att);
    u32 hw[8] = {h0.x, h0.y, h0.z, h0.w, h1.x, h1.y, h1.z, h1.w};
#pragma unroll
    for (int j = 0; j < 8; j++) {
      UH hv;
      hv.u = hw[j];
      mpk[j] = att2.h * hv.h + mpk[j];  // v_pk_fma_f16
    }
    mt = fmaf(att, pp.y, mt);
  }
  // cross-group reduce (offsets 8,16,32)
#pragma unroll
  for (int off = 8; off <= 32; off <<= 1) {
#pragma unroll
    for (int j = 0; j < 8; j++) {
      UH v;
      v.h = mpk[j];
      UH s;
      s.u = (u32)__shfl_xor((int)v.u, off);
      mpk[j] = v.h + s.h;
    }
    mt += __shfl_xor(mt, off);
  }
  // lsq over the full spatial vector (slots partitioned across o; reduce 1,2,4)
  float lp = 0.f;
#pragma unroll
  for (int j = 0; j < 8; j++) {
    float lo = (float)mpk[j][0], hi = (float)mpk[j][1];
    lp = fmaf(lo, lo, lp);
    lp = fmaf(hi, hi, lp);
  }
  lp += __shfl_xor(lp, 1);
  lp += __shfl_xor(lp, 2);
  lp += __shfl_xor(lp, 4);
  float lsq = lp;
  float neg_inner = mt * mt - lsq;
  float denom = sqrtf(fmaxf(neg_inner, 1e-9f));
  float r = sc / denom;
  float ssq = r * r * lsq;
  float agg0 = sqrtf(c + ssq);
  float ynA = fmaxf(sqrtf(ssq), 1e-9f);
  float v2 = fmaxf(agg0 / sc, 1.f + EPSH);
  float dA = sc * 0.69314718056f * __log2f(v2 + sqrtf(v2 * v2 - 1.f));
  float sca = dA * r / ynA;
  if (g == 0) {
    const u32* tp = T + (size_t)node * 128 + o * 8;
    uint4 t0 = *(const uint4*)tp;
    uint4 t0b = *(const uint4*)(tp + 4);
    uint4 t1 = *(const uint4*)(tp + 64);
    uint4 t1b = *(const uint4*)(tp + 68);
    u32 tw[8] = {t0.x, t0.y, t0.z, t0.w, t0b.x, t0b.y, t0b.z, t0b.w};
    u32 tv[8] = {t1.x, t1.y, t1.z, t1.w, t1b.x, t1b.y, t1b.z, t1b.w};
    float oe = 1.f + eps;
    u32 olo[8], ohi[8];
#pragma unroll
    for (int j = 0; j < 8; j++) {
      float lo = (float)mpk[j][0], hi = (float)mpk[j][1];
      olo[j] = packhl(fmaf(sca, lo, oe * rec(tw[j])));
      ohi[j] = packhl(fmaf(sca, hi, oe * rec(tv[j])));
    }
    u32* op = Tout + (size_t)node * 128 + o * 8;
    *(uint4*)op = make_uint4(olo[0], olo[1], olo[2], olo[3]);
    *(uint4*)(op + 4) = make_uint4(olo[4], olo[5], olo[6], olo[7]);
    *(uint4*)(op + 64) = make_uint4(ohi[0], ohi[1], ohi[2], ohi[3]);
    *(uint4*)(op + 68) = make_uint4(ohi[4], ohi[5], ohi[6], ohi[7]);
  }
}

// ---------------- pooling ----------------
__global__ void k_pool(const u32* __restrict__ U, const int* __restrict__ gptr,
                       float* __restrict__ out, int layer) {
  int g = blockIdx.x;
  int c = threadIdx.x;  // 0..127
  int s = gptr[g], e = gptr[g + 1];
  float acc = 0.f;
  if (c > 0) {
    const u32* up = U + (c - 1);
    int i = s;
    float a0 = 0.f, a1 = 0.f, a2 = 0.f, a3 = 0.f;
    for (; i + 3 < e; i += 4) {
      a0 += rec(up[(size_t)i * 128]);
      a1 += rec(up[(size_t)(i + 1) * 128]);
      a2 += rec(up[(size_t)(i + 2) * 128]);
      a3 += rec(up[(size_t)(i + 3) * 128]);
    }
    for (; i < e; i++) a0 += rec(up[(size_t)i * 128]);
    acc = (a0 + a1) + (a2 + a3);
  }
  out[(size_t)g * 256 + layer * 128 + c] = acc;
}

// ---------------- launch ----------------
extern "C" void kernel_launch(void* const* d_in, const int* in_sizes, int n_in, void* d_out,
                              int out_size, void* d_ws, size_t ws_size, hipStream_t stream) {
  const float* x = (const float*)d_in[0];
  const float* cptr = (const float*)d_in[1];
  const float* w_in = (const float*)d_in[2];
  const float* att_w = (const float*)d_in[3];
  const float* att_b = (const float*)d_in[4];
  const float* epsv = (const float*)d_in[5];
  const float* mlp_w = (const float*)d_in[6];
  const float* mlp_b = (const float*)d_in[7];
  const int* ei = (const int*)d_in[8];
  const int* batch = (const int*)d_in[9];
  const int* srcp = ei;
  const int* dstp = ei + EE;
  float* out = (float*)d_out;

  u32* ws = (u32*)d_ws;
  u16* Wfh = (u16*)ws;  // WF_TOT u16
  u16* Wfl = Wfh + WF_TOT;
  int* deg = (int*)(ws + 126976);  // N
  int* rowp = deg + NN;            // N+1
  int* cursor = rowp + NN + 1;     // N
  int* gptr = cursor + NN;         // G+1
  int* dsts = gptr + GG + 1;       // E
  size_t o1 = (size_t)((u32*)(dsts + EE) - ws);
  o1 = (o1 + 3) & ~(size_t)3;
  float2* ptHH = (float2*)(ws + o1);   // NNP float2
  u32* HHh = ws + o1 + 2 * NNP;        // NNP*128 (HL | H), half2 slots
  u32* A32 = HHh + (size_t)NNP * 128;  // NNP*128 packhl tangent
  u32* B32 = A32 + (size_t)NNP * 128;  // NNP*128

  const int EW = 12500;  // agg: 4 nodes/block
  const int GEMMG = (NN + 63) / 64;
  float* ptF = (float*)ptHH;

  (void)hipMemsetAsync(deg, 0, NN * sizeof(int), stream);
  k_prep_wf<<<64, 256, 0, stream>>>(att_w, mlp_w, w_in, Wfh, Wfl);
  k_count<<<(EE + 255) / 256, 256, 0, stream>>>(srcp, EE, deg);
  k_gptr<<<3, 256, 0, stream>>>(batch, gptr);
  k_scan_excl<<<1, 1024, 0, stream>>>(deg, NN, rowp, cursor);
  k_scatter<<<(EE + 255) / 256, 256, 0, stream>>>(srcp, dstp, EE, cursor, dsts);

#define WH(m) (Wfh + 28672 + (m) * 16384)
#define WL(m) (Wfl + 28672 + (m) * 16384)

  // input GEMM + att0: T0 -> A32 ; H0 -> (HHh+64, ptF odd) ; HL0 -> (HHh, ptF even)
  k_gemm_in<<<GEMMG, 256, 0, stream>>>(x, Wfh, Wfl, WH(0), WL(0), att_b, A32, HHh, ptF, cptr, NN);

  // ---- layer 0 ----
  k_agg_o<<<EW, 256, 0, stream>>>(HHh, ptHH, A32, rowp, dsts, epsv + 0, cptr, B32, NN);
  k_mlp3<0><<<GEMMG, 256, 0, stream>>>(B32, WH(2), WL(2), mlp_b + 0 * DD, WH(3), WL(3),
                                       mlp_b + 1 * DD, WH(1), WL(1), att_b + DD, A32, HHh, ptF,
                                       cptr, NN);
  k_pool<<<GG, 128, 0, stream>>>(A32, gptr, out, 0);

  // ---- layer 1 ----
  k_agg_o<<<EW, 256, 0, stream>>>(HHh, ptHH, A32, rowp, dsts, epsv + 1, cptr, B32, NN);
  k_mlp3<1><<<GEMMG, 256, 0, stream>>>(B32, WH(4), WL(4), mlp_b + 2 * DD, WH(5), WL(5),
                                       mlp_b + 3 * DD, nullptr, nullptr, nullptr, B32, nullptr,
                                       nullptr, cptr, NN);
  k_pool<<<GG, 128, 0, stream>>>(B32, gptr, out, 1);
}